// Round 6
// baseline (556.901 us; speedup 1.0000x reference)
//
#include <hip/hip_runtime.h>
#include <hip/hip_bf16.h>
#include <math.h>

#define G_ 32
#define H_ 12
#define D_ 768
#define HD_ 64
#define FF_ 3072
#define B_ 2
#define T_ 2048
#define SPAN_ 63
#define SPANC_ 129
#define EPSF 1e-5f

// zero-slot sentinels for the packed bias table
#define REL_ZOFF 47628   // 3969*12 (valid rel offsets are pre-multiplied by 12, max 47616)
#define DEMO_ZIDX 8127   // valid demo idx max 8126
#define RELZ_N ((3969 + 1) * 12)   // 47640 floats
#define DEMOZ_N ((8127 + 1) * 12)  // 97536 floats

typedef short bf16x8 __attribute__((ext_vector_type(8)));
typedef short short4v __attribute__((ext_vector_type(4)));
typedef float f32x4 __attribute__((ext_vector_type(4)));

__device__ __forceinline__ short f2bf(float f) {
    unsigned u = __builtin_bit_cast(unsigned, f);
    u = u + 0x7FFFu + ((u >> 16) & 1u);
    return (short)(u >> 16);
}

// ---------------- LayerNorm (f32 in -> bf16 out): one wave per row ----------------
__global__ __launch_bounds__(256) void ln_bf16_kernel(const float* __restrict__ x,
                                                      const float* __restrict__ w,
                                                      const float* __restrict__ b,
                                                      short* __restrict__ out) {
    int wv = threadIdx.x >> 6;
    int lane = threadIdx.x & 63;
    int rowi = blockIdx.x * 4 + wv;
    const float* xr = x + (size_t)rowi * D_;
    float vals[12];
    float s = 0.f;
#pragma unroll
    for (int i = 0; i < 12; ++i) { vals[i] = xr[lane + i * 64]; s += vals[i]; }
#pragma unroll
    for (int off = 32; off > 0; off >>= 1) s += __shfl_xor(s, off, 64);
    float mean = s * (1.0f / D_);
    float vs = 0.f;
#pragma unroll
    for (int i = 0; i < 12; ++i) { float d = vals[i] - mean; vs += d * d; }
#pragma unroll
    for (int off = 32; off > 0; off >>= 1) vs += __shfl_xor(vs, off, 64);
    float rstd = rsqrtf(vs * (1.0f / D_) + EPSF);
    short* outr = out + (size_t)rowi * D_;
#pragma unroll
    for (int i = 0; i < 12; ++i) {
        int c = lane + i * 64;
        outr[c] = f2bf((vals[i] - mean) * rstd * w[c] + b[c]);
    }
}

// ---------------- transpose-cast: W [K][N] f32 -> Wt [N][K] bf16 ----------------
__global__ __launch_bounds__(256) void tcast_kernel(const float* __restrict__ W,
                                                    short* __restrict__ Wt,
                                                    int K, int N) {
    __shared__ float t[32][33];
    int n0 = blockIdx.x * 32, k0 = blockIdx.y * 32;
    int tid = threadIdx.x;
    int r = tid >> 3, c4 = (tid & 7) * 4;
    float4 v = *(const float4*)(W + (size_t)(k0 + r) * N + n0 + c4);
    t[r][c4 + 0] = v.x; t[r][c4 + 1] = v.y; t[r][c4 + 2] = v.z; t[r][c4 + 3] = v.w;
    __syncthreads();
    short4v o;
    o[0] = f2bf(t[c4 + 0][r]); o[1] = f2bf(t[c4 + 1][r]);
    o[2] = f2bf(t[c4 + 2][r]); o[3] = f2bf(t[c4 + 3][r]);
    *(short4v*)(Wt + (size_t)(n0 + r) * K + k0 + c4) = o;
}

// ---------------- pad-copy: dst[0..nsrc)=src, [nsrc..ntot)=0 ----------------
__global__ __launch_bounds__(256) void padcopy_kernel(const float* __restrict__ src,
                                                      float* __restrict__ dst,
                                                      int nsrc, int ntot) {
    int i = blockIdx.x * 256 + threadIdx.x;
    if (i < ntot) dst[i] = (i < nsrc) ? src[i] : 0.f;
}

// ---------------- packed bias-index table: packed[q][k] ----------------
__global__ __launch_bounds__(256) void pack_kernel(const int* __restrict__ rowp,
                                                   const int* __restrict__ colp,
                                                   const int* __restrict__ drowp,
                                                   const int* __restrict__ dcolp,
                                                   const int* __restrict__ didp,
                                                   unsigned* __restrict__ packed) {
    int idx = blockIdx.x * 256 + threadIdx.x;  // [0, T*T)
    int q = idx >> 11, k = idx & (T_ - 1);
    int idq = didp[q], idk = didp[k];
    bool valid = (idq >= 0) && (idk >= 0);
    unsigned rel = REL_ZOFF, dem = DEMO_ZIDX;
    if (valid) {
        int dr = min(max(rowp[q] - rowp[k], -(G_ - 1)), G_ - 1) + (G_ - 1);
        int dc = min(max(colp[q] - colp[k], -(G_ - 1)), G_ - 1) + (G_ - 1);
        rel = (unsigned)(dr * SPAN_ + dc) * 12u;
        if (idq == idk) {
            int ddr = min(max(drowp[q] - drowp[k], -(G_ - 1)), G_ - 1) + (G_ - 1);
            int ddc = min(max(dcolp[q] - dcolp[k], -2 * G_), 2 * G_) + 2 * G_;
            dem = (unsigned)(ddr * SPANC_ + ddc);
        }
    }
    packed[idx] = rel | (dem << 16);
}

// ---------------- bf16 MFMA GEMM: C = A[M][K] * Bt[N][K]^T ----------------
enum { EPI_NONE = 0, EPI_RES = 1, EPI_GELU = 2 };

template <int EPI, int BF16OUT>
__global__ __launch_bounds__(256, 2) void gemm_bf16(const short* __restrict__ A,
                                                    const short* __restrict__ Bt,
                                                    const float* __restrict__ bias,
                                                    const float* __restrict__ res,
                                                    void* __restrict__ Cv,
                                                    int M, int N, int K) {
    __shared__ short As[128 * 64];
    __shared__ short Bs[128 * 64];
    int tid = threadIdx.x;
    int l = tid & 63;
    int w = tid >> 6;
    int wm = w >> 1, wn = w & 1;
    int row0 = blockIdx.y * 128, col0 = blockIdx.x * 128;
    int g = l >> 4, c16 = l & 15;
    f32x4 zero = {0.f, 0.f, 0.f, 0.f};
    f32x4 acc[4][4];
#pragma unroll
    for (int m = 0; m < 4; ++m)
#pragma unroll
        for (int n = 0; n < 4; ++n) acc[m][n] = zero;

    for (int k0 = 0; k0 < K; k0 += 64) {
#pragma unroll
        for (int p = 0; p < 4; ++p) {
            int sidx = p * 256 + tid;
            int row = sidx >> 3, cseg = sidx & 7;
            int ds = row * 64 + ((cseg ^ (row & 7)) << 3);
            *(bf16x8*)&As[ds] = *(const bf16x8*)(A + (size_t)(row0 + row) * K + k0 + cseg * 8);
            *(bf16x8*)&Bs[ds] = *(const bf16x8*)(Bt + (size_t)(col0 + row) * K + k0 + cseg * 8);
        }
        __syncthreads();
#pragma unroll
        for (int dk = 0; dk < 2; ++dk) {
            bf16x8 af[4], bfr[4];
#pragma unroll
            for (int m = 0; m < 4; ++m) {
                int r = wm * 64 + m * 16 + c16;
                af[m] = *(const bf16x8*)&As[r * 64 + (((dk * 4 + g) ^ (r & 7)) << 3)];
            }
#pragma unroll
            for (int n = 0; n < 4; ++n) {
                int r = wn * 64 + n * 16 + c16;
                bfr[n] = *(const bf16x8*)&Bs[r * 64 + (((dk * 4 + g) ^ (r & 7)) << 3)];
            }
#pragma unroll
            for (int m = 0; m < 4; ++m)
#pragma unroll
                for (int n = 0; n < 4; ++n)
                    acc[m][n] = __builtin_amdgcn_mfma_f32_16x16x32_bf16(af[m], bfr[n], acc[m][n], 0, 0, 0);
        }
        __syncthreads();
    }

#pragma unroll
    for (int m = 0; m < 4; ++m)
#pragma unroll
        for (int n = 0; n < 4; ++n) {
            int rrow = row0 + wm * 64 + m * 16 + g * 4;
            int ccol = col0 + wn * 64 + n * 16 + c16;
            float bv = bias[ccol];
#pragma unroll
            for (int i = 0; i < 4; ++i) {
                float v = acc[m][n][i] + bv;
                if (EPI == EPI_GELU) v = 0.5f * v * (1.f + erff(v * 0.70710678118f));
                if (EPI == EPI_RES) v += res[(size_t)(rrow + i) * N + ccol];
                if (BF16OUT)
                    ((short*)Cv)[(size_t)(rrow + i) * N + ccol] = f2bf(v);
                else
                    ((float*)Cv)[(size_t)(rrow + i) * N + ccol] = v;
            }
        }
}

// ---------------- fused MFMA flash attention, table-driven bias ----------------
// Block: 256 thr (4 waves), QBLK=64 (wave w owns q-rows w*16..+15), KBLK=64.
// Round-4 structure (passed post-timing) + static-max softmax (scores bounded,
// exp without max-sub is exact after normalization) + 1-deep packed prefetch.
__global__ __launch_bounds__(256, 2) void attn_mfma(
    const short* __restrict__ qkv,
    const unsigned* __restrict__ packed,
    const float* __restrict__ relz, const float* __restrict__ demoz,
    short* __restrict__ attn_o) {
    __shared__ short Ks[64 * 64];     // XOR-seg swizzled (by row&7)
    __shared__ short Vt[64 * 72];     // V^T [d][k], k-chunk XOR-swizzled by d>>3
    __shared__ short Pb[4][16 * 72];  // per-wave P, k-chunk XOR-swizzled by q>>2

    int tid = threadIdx.x, w = tid >> 6, l = tid & 63;
    int g = l >> 4, c16 = l & 15;
    int qt = blockIdx.x & 31, bh = blockIdx.x >> 5;
    int h = bh % H_, b = bh / H_;
    int q0 = qt * 64;
    const int QS = 3 * D_;
    const short* kvbase = qkv + (size_t)b * T_ * QS;

    // Q fragments (A-operand: row = lane&15, k contiguous per group)
    bf16x8 qf[2];
    {
        int qrow = q0 + w * 16 + c16;
        const short* qp = kvbase + (size_t)qrow * QS + h * HD_;
#pragma unroll
        for (int dk = 0; dk < 2; ++dk) qf[dk] = *(const bf16x8*)(qp + dk * 32 + g * 8);
    }
    // packed-table row base for each of this lane's 4 q-rows
    const unsigned* prow[4];
#pragma unroll
    for (int i = 0; i < 4; ++i)
        prow[i] = packed + (size_t)(q0 + w * 16 + g * 4 + i) * T_;

    f32x4 zero = {0.f, 0.f, 0.f, 0.f};
    f32x4 oacc[4];
#pragma unroll
    for (int nf = 0; nf < 4; ++nf) oacc[nf] = zero;
    float lsum[4] = {0.f, 0.f, 0.f, 0.f};

    // 1-deep prefetch of the packed bias indices (j = nf*4 + i)
    unsigned pk[16];
#pragma unroll
    for (int j = 0; j < 16; ++j) pk[j] = prow[j & 3][(j >> 2) * 16 + c16];

    for (int kb = 0; kb < T_; kb += 64) {
        // ---- stage K (seg-swizzled) ----
#pragma unroll
        for (int p = 0; p < 2; ++p) {
            int sidx = p * 256 + tid;
            int row = sidx >> 3, cseg = sidx & 7;
            *(bf16x8*)&Ks[row * 64 + ((cseg ^ (row & 7)) << 3)] =
                *(const bf16x8*)(kvbase + (size_t)(kb + row) * QS + D_ + h * HD_ + cseg * 8);
        }
        // ---- stage V^T with chunk swizzle: slot(k) = ((k>>3)^(d>>3))*8 + (k&7) ----
        {
            int vrow = tid >> 2, part = tid & 3;
            const short* vp = kvbase + (size_t)(kb + vrow) * QS + 2 * D_ + h * HD_ + part * 16;
            bf16x8 v0 = *(const bf16x8*)(vp);
            bf16x8 v1 = *(const bf16x8*)(vp + 8);
            int kchunk = vrow >> 3, kpos = vrow & 7;
#pragma unroll
            for (int j = 0; j < 8; ++j) {
                int d = part * 16 + j;
                Vt[d * 72 + (((kchunk ^ (d >> 3)) & 7) << 3) + kpos] = v0[j];
            }
#pragma unroll
            for (int j = 0; j < 8; ++j) {
                int d = part * 16 + 8 + j;
                Vt[d * 72 + (((kchunk ^ (d >> 3)) & 7) << 3) + kpos] = v1[j];
            }
        }
        // ---- bias gathers for THIS tile (pk resident since last iteration) ----
        float br[16], bd[16];
#pragma unroll
        for (int j = 0; j < 16; ++j) {
            br[j] = relz[(pk[j] & 0xFFFFu) + h];
            bd[j] = demoz[(pk[j] >> 16) * 12u + h];
        }
        // ---- prefetch next tile's packed indices ----
        unsigned pknext[16];
        {
            int kbn = (kb + 64) & (T_ - 1);
#pragma unroll
            for (int j = 0; j < 16; ++j) pknext[j] = prow[j & 3][kbn + (j >> 2) * 16 + c16];
        }
        __syncthreads();

        // ---- QK^T ----
        f32x4 sac[4];
#pragma unroll
        for (int nf = 0; nf < 4; ++nf) sac[nf] = zero;
#pragma unroll
        for (int dk = 0; dk < 2; ++dk) {
#pragma unroll
            for (int nf = 0; nf < 4; ++nf) {
                int r = nf * 16 + c16;
                bf16x8 kf = *(const bf16x8*)&Ks[r * 64 + (((dk * 4 + g) ^ (r & 7)) << 3)];
                sac[nf] = __builtin_amdgcn_mfma_f32_16x16x32_bf16(qf[dk], kf, sac[nf], 0, 0, 0);
            }
        }

        // ---- static-max softmax: p = exp(s*scale + bias), per-lane partial sum ----
        float pp[4][4];
#pragma unroll
        for (int nf = 0; nf < 4; ++nf)
#pragma unroll
            for (int i = 0; i < 4; ++i) {
                int j = nf * 4 + i;
                float e = __expf(fmaf(sac[nf][i], 0.125f, br[j] + bd[j]));
                pp[nf][i] = e;
                lsum[i] += e;
            }
        // ---- P -> wave-private LDS (chunk-swizzled by g) ----
        short* pbw = &Pb[w][0];
#pragma unroll
        for (int nf = 0; nf < 4; ++nf) {
            int chunkbase = nf * 2 + (c16 >> 3);
            int kpos = c16 & 7;
#pragma unroll
            for (int i = 0; i < 4; ++i)
                pbw[(g * 4 + i) * 72 + (((chunkbase ^ g) & 7) << 3) + kpos] = f2bf(pp[nf][i]);
        }
        // ---- PV ----
#pragma unroll
        for (int dk = 0; dk < 2; ++dk) {
            bf16x8 pa = *(const bf16x8*)&pbw[c16 * 72 + (((dk * 4 + g) ^ (c16 >> 2)) & 7) * 8];
#pragma unroll
            for (int nf = 0; nf < 4; ++nf) {
                int d = nf * 16 + c16;
                bf16x8 vb = *(const bf16x8*)&Vt[d * 72 + (((dk * 4 + g) ^ (d >> 3)) & 7) * 8];
                oacc[nf] = __builtin_amdgcn_mfma_f32_16x16x32_bf16(pa, vb, oacc[nf], 0, 0, 0);
            }
        }
#pragma unroll
        for (int j = 0; j < 16; ++j) pk[j] = pknext[j];
        __syncthreads();
    }

    // ---- one-time denominator reduction across the 16 lanes of each row ----
#pragma unroll
    for (int i = 0; i < 4; ++i) {
#pragma unroll
        for (int off = 1; off < 16; off <<= 1) lsum[i] += __shfl_xor(lsum[i], off, 64);
    }

    // ---- finalize ----
#pragma unroll
    for (int nf = 0; nf < 4; ++nf)
#pragma unroll
        for (int i = 0; i < 4; ++i) {
            float o = oacc[nf][i] / lsum[i];
            int qq = q0 + w * 16 + g * 4 + i;
            attn_o[(size_t)(b * T_ + qq) * D_ + h * HD_ + nf * 16 + c16] = f2bf(o);
        }
}

// ---------------- launcher ----------------
extern "C" void kernel_launch(void* const* d_in, const int* in_sizes, int n_in,
                              void* d_out, int out_size, void* d_ws, size_t ws_size,
                              hipStream_t stream) {
    const float* x = (const float*)d_in[0];
    const int* rowp = (const int*)d_in[1];
    const int* colp = (const int*)d_in[2];
    const int* drowp = (const int*)d_in[3];
    const int* dcolp = (const int*)d_in[4];
    const int* didp = (const int*)d_in[5];
    // d_in[6] = is_sep (bool) — unused: is_sep <=> demo_id < 0 by construction
    const float* ln1_w = (const float*)d_in[7];
    const float* ln1_b = (const float*)d_in[8];
    const float* ln2_w = (const float*)d_in[9];
    const float* ln2_b = (const float*)d_in[10];
    const float* qkv_w = (const float*)d_in[11];
    const float* qkv_b = (const float*)d_in[12];
    const float* proj_w = (const float*)d_in[13];
    const float* proj_b = (const float*)d_in[14];
    const float* ff1_w = (const float*)d_in[15];
    const float* ff1_b = (const float*)d_in[16];
    const float* ff2_w = (const float*)d_in[17];
    const float* ff2_b = (const float*)d_in[18];
    const float* rel_emb = (const float*)d_in[19];
    const float* demo_emb = (const float*)d_in[20];
    float* out = (float*)d_out;

    const int M = B_ * T_;  // 4096
    char* p = (char*)d_ws;
    short* h1 = (short*)p;     p += (size_t)M * D_ * 2;
    short* qkvb = (short*)p;   p += (size_t)M * 3 * D_ * 2;
    short* attn_o = (short*)p; p += (size_t)M * D_ * 2;
    float* x2 = (float*)p;     p += (size_t)M * D_ * 4;
    short* h2 = (short*)p;     p += (size_t)M * D_ * 2;
    char* ffact_base = p;      p += (size_t)M * FF_ * 2;   // 25.2 MB region
    short* qkvt = (short*)p;   p += (size_t)(3 * D_) * D_ * 2;
    short* projt = (short*)p;  p += (size_t)D_ * D_ * 2;
    short* ff1t = (short*)p;   p += (size_t)FF_ * D_ * 2;
    short* ff2t = (short*)p;   p += (size_t)D_ * FF_ * 2;

    // bias table aliases the ffact region (ffact written only after attention)
    short* ffact = (short*)ffact_base;
    unsigned* packed = (unsigned*)ffact_base;                       // 16 MB
    float* relz = (float*)(ffact_base + (size_t)T_ * T_ * 4);       // 190.6 KB
    float* demoz = relz + RELZ_N;                                   // 390.1 KB

    // ---- precompute ----
    tcast_kernel<<<dim3(3 * D_ / 32, D_ / 32), 256, 0, stream>>>(qkv_w, qkvt, D_, 3 * D_);
    tcast_kernel<<<dim3(D_ / 32, D_ / 32), 256, 0, stream>>>(proj_w, projt, D_, D_);
    tcast_kernel<<<dim3(FF_ / 32, D_ / 32), 256, 0, stream>>>(ff1_w, ff1t, D_, FF_);
    tcast_kernel<<<dim3(D_ / 32, FF_ / 32), 256, 0, stream>>>(ff2_w, ff2t, FF_, D_);
    padcopy_kernel<<<dim3((RELZ_N + 255) / 256), 256, 0, stream>>>(rel_emb, relz, SPAN_ * SPAN_ * H_, RELZ_N);
    padcopy_kernel<<<dim3((DEMOZ_N + 255) / 256), 256, 0, stream>>>(demo_emb, demoz, SPANC_ * SPAN_ * H_, DEMOZ_N);
    pack_kernel<<<dim3(T_ * T_ / 256), 256, 0, stream>>>(rowp, colp, drowp, dcolp, didp, packed);

    // ---- main pipeline ----
    ln_bf16_kernel<<<dim3(M / 4), 256, 0, stream>>>(x, ln1_w, ln1_b, h1);

    gemm_bf16<EPI_NONE, 1><<<dim3(3 * D_ / 128, M / 128), 256, 0, stream>>>(
        h1, qkvt, qkv_b, nullptr, qkvb, M, 3 * D_, D_);

    attn_mfma<<<dim3(B_ * H_ * (T_ / 64)), 256, 0, stream>>>(
        qkvb, packed, relz, demoz, attn_o);

    gemm_bf16<EPI_RES, 0><<<dim3(D_ / 128, M / 128), 256, 0, stream>>>(
        attn_o, projt, proj_b, x, x2, M, D_, D_);

    ln_bf16_kernel<<<dim3(M / 4), 256, 0, stream>>>(x2, ln2_w, ln2_b, h2);

    gemm_bf16<EPI_GELU, 1><<<dim3(FF_ / 128, M / 128), 256, 0, stream>>>(
        h2, ff1t, ff1_b, nullptr, ffact, M, FF_, D_);

    gemm_bf16<EPI_RES, 0><<<dim3(D_ / 128, M / 128), 256, 0, stream>>>(
        ffact, ff2t, ff2_b, x2, out, M, D_, FF_);
}

// Round 7
// 277.129 us; speedup vs baseline: 2.0095x; 2.0095x over previous
//
#include <hip/hip_runtime.h>
#include <hip/hip_bf16.h>
#include <math.h>

#define G_ 32
#define H_ 12
#define D_ 768
#define HD_ 64
#define FF_ 3072
#define B_ 2
#define T_ 2048
#define SPAN_ 63
#define SPANC_ 129
#define EPSF 1e-5f

typedef short bf16x8 __attribute__((ext_vector_type(8)));
typedef short short4v __attribute__((ext_vector_type(4)));
typedef float f32x4 __attribute__((ext_vector_type(4)));

__device__ __forceinline__ short f2bf(float f) {
    unsigned u = __builtin_bit_cast(unsigned, f);
    u = u + 0x7FFFu + ((u >> 16) & 1u);
    return (short)(u >> 16);
}

// ---------------- LayerNorm (f32 in -> bf16 out): one wave per row ----------------
__global__ __launch_bounds__(256) void ln_bf16_kernel(const float* __restrict__ x,
                                                      const float* __restrict__ w,
                                                      const float* __restrict__ b,
                                                      short* __restrict__ out) {
    int wv = threadIdx.x >> 6;
    int lane = threadIdx.x & 63;
    int rowi = blockIdx.x * 4 + wv;
    const float* xr = x + (size_t)rowi * D_;
    float vals[12];
    float s = 0.f;
#pragma unroll
    for (int i = 0; i < 12; ++i) { vals[i] = xr[lane + i * 64]; s += vals[i]; }
#pragma unroll
    for (int off = 32; off > 0; off >>= 1) s += __shfl_xor(s, off, 64);
    float mean = s * (1.0f / D_);
    float vs = 0.f;
#pragma unroll
    for (int i = 0; i < 12; ++i) { float d = vals[i] - mean; vs += d * d; }
#pragma unroll
    for (int off = 32; off > 0; off >>= 1) vs += __shfl_xor(vs, off, 64);
    float rstd = rsqrtf(vs * (1.0f / D_) + EPSF);
    short* outr = out + (size_t)rowi * D_;
#pragma unroll
    for (int i = 0; i < 12; ++i) {
        int c = lane + i * 64;
        outr[c] = f2bf((vals[i] - mean) * rstd * w[c] + b[c]);
    }
}

// ---------------- transpose-cast: W [K][N] f32 -> Wt [N][K] bf16 ----------------
__global__ __launch_bounds__(256) void tcast_kernel(const float* __restrict__ W,
                                                    short* __restrict__ Wt,
                                                    int K, int N) {
    __shared__ float t[32][33];
    int n0 = blockIdx.x * 32, k0 = blockIdx.y * 32;
    int tid = threadIdx.x;
    int r = tid >> 3, c4 = (tid & 7) * 4;
    float4 v = *(const float4*)(W + (size_t)(k0 + r) * N + n0 + c4);
    t[r][c4 + 0] = v.x; t[r][c4 + 1] = v.y; t[r][c4 + 2] = v.z; t[r][c4 + 3] = v.w;
    __syncthreads();
    short4v o;
    o[0] = f2bf(t[c4 + 0][r]); o[1] = f2bf(t[c4 + 1][r]);
    o[2] = f2bf(t[c4 + 2][r]); o[3] = f2bf(t[c4 + 3][r]);
    *(short4v*)(Wt + (size_t)(n0 + r) * K + k0 + c4) = o;
}

// ---------------- bias materialization: biasT[h][q][k] bf16 ----------------
// One block: 16 q-rows x 64 k-cols patch for ALL 12 heads.
// Per (q,k): 2 row-gathers of 48B (rel_emb/demo_emb rows are 12 contiguous f32),
// staged in LDS, written out coalesced per-h plane.
__global__ __launch_bounds__(256) void bias_build(
    const int* __restrict__ rowp, const int* __restrict__ colp,
    const int* __restrict__ drowp, const int* __restrict__ dcolp,
    const int* __restrict__ didp,
    const float* __restrict__ rel_emb, const float* __restrict__ demo_emb,
    ushort* __restrict__ biasT) {
    __shared__ ushort patch[12][16][72];  // pad 72: qi-stride 36 dw -> 2-way max
    int k0 = blockIdx.x * 64, q0 = blockIdx.y * 16;
    int tid = threadIdx.x;
    int qi = tid >> 4, kq = (tid & 15) * 4;
    int q = q0 + qi;
    int idq = didp[q];
    int rq = rowp[q], cq = colp[q], drq = drowp[q], dcq = dcolp[q];
#pragma unroll
    for (int j = 0; j < 4; ++j) {
        int k = k0 + kq + j;
        int idk = didp[k];
        float4 v0 = {0.f, 0.f, 0.f, 0.f}, v1 = v0, v2 = v0;
        if (idq >= 0 && idk >= 0) {
            int dr = min(max(rq - rowp[k], -(G_ - 1)), G_ - 1) + (G_ - 1);
            int dc = min(max(cq - colp[k], -(G_ - 1)), G_ - 1) + (G_ - 1);
            const float* rp = rel_emb + (size_t)(dr * SPAN_ + dc) * 12;  // 48B-aligned
            v0 = *(const float4*)rp;
            v1 = *(const float4*)(rp + 4);
            v2 = *(const float4*)(rp + 8);
            if (idq == idk) {
                int ddr = min(max(drq - drowp[k], -(G_ - 1)), G_ - 1) + (G_ - 1);
                int ddc = min(max(dcq - dcolp[k], -2 * G_), 2 * G_) + 2 * G_;
                const float* dp = demo_emb + (size_t)(ddr * SPANC_ + ddc) * 12;
                float4 w0 = *(const float4*)dp;
                float4 w1 = *(const float4*)(dp + 4);
                float4 w2 = *(const float4*)(dp + 8);
                v0.x += w0.x; v0.y += w0.y; v0.z += w0.z; v0.w += w0.w;
                v1.x += w1.x; v1.y += w1.y; v1.z += w1.z; v1.w += w1.w;
                v2.x += w2.x; v2.y += w2.y; v2.z += w2.z; v2.w += w2.w;
            }
        }
        float bv[12] = {v0.x, v0.y, v0.z, v0.w, v1.x, v1.y, v1.z, v1.w,
                        v2.x, v2.y, v2.z, v2.w};
        int kl = kq + j;
#pragma unroll
        for (int h = 0; h < 12; ++h) patch[h][qi][kl] = (ushort)f2bf(bv[h]);
    }
    __syncthreads();
    // writeout: 12 planes x 16 rows x 128B = 1536 chunks of 16B
    for (int c = tid; c < 1536; c += 256) {
        int rowid = c >> 3, off = (c & 7) * 8;
        int h = rowid >> 4, q2 = rowid & 15;
        *(bf16x8*)(biasT + (size_t)h * T_ * T_ + (size_t)(q0 + q2) * T_ + k0 + off) =
            *(const bf16x8*)&patch[h][q2][off];
    }
}

// ---------------- bf16 MFMA GEMM: C = A[M][K] * Bt[N][K]^T ----------------
enum { EPI_NONE = 0, EPI_RES = 1, EPI_GELU = 2 };

template <int EPI, int BF16OUT>
__global__ __launch_bounds__(256, 2) void gemm_bf16(const short* __restrict__ A,
                                                    const short* __restrict__ Bt,
                                                    const float* __restrict__ bias,
                                                    const float* __restrict__ res,
                                                    void* __restrict__ Cv,
                                                    int M, int N, int K) {
    __shared__ short As[128 * 64];
    __shared__ short Bs[128 * 64];
    int tid = threadIdx.x;
    int l = tid & 63;
    int w = tid >> 6;
    int wm = w >> 1, wn = w & 1;
    int row0 = blockIdx.y * 128, col0 = blockIdx.x * 128;
    int g = l >> 4, c16 = l & 15;
    f32x4 zero = {0.f, 0.f, 0.f, 0.f};
    f32x4 acc[4][4];
#pragma unroll
    for (int m = 0; m < 4; ++m)
#pragma unroll
        for (int n = 0; n < 4; ++n) acc[m][n] = zero;

    for (int k0 = 0; k0 < K; k0 += 64) {
#pragma unroll
        for (int p = 0; p < 4; ++p) {
            int sidx = p * 256 + tid;
            int row = sidx >> 3, cseg = sidx & 7;
            int ds = row * 64 + ((cseg ^ (row & 7)) << 3);
            *(bf16x8*)&As[ds] = *(const bf16x8*)(A + (size_t)(row0 + row) * K + k0 + cseg * 8);
            *(bf16x8*)&Bs[ds] = *(const bf16x8*)(Bt + (size_t)(col0 + row) * K + k0 + cseg * 8);
        }
        __syncthreads();
#pragma unroll
        for (int dk = 0; dk < 2; ++dk) {
            bf16x8 af[4], bfr[4];
#pragma unroll
            for (int m = 0; m < 4; ++m) {
                int r = wm * 64 + m * 16 + c16;
                af[m] = *(const bf16x8*)&As[r * 64 + (((dk * 4 + g) ^ (r & 7)) << 3)];
            }
#pragma unroll
            for (int n = 0; n < 4; ++n) {
                int r = wn * 64 + n * 16 + c16;
                bfr[n] = *(const bf16x8*)&Bs[r * 64 + (((dk * 4 + g) ^ (r & 7)) << 3)];
            }
#pragma unroll
            for (int m = 0; m < 4; ++m)
#pragma unroll
                for (int n = 0; n < 4; ++n)
                    acc[m][n] = __builtin_amdgcn_mfma_f32_16x16x32_bf16(af[m], bfr[n], acc[m][n], 0, 0, 0);
        }
        __syncthreads();
    }

#pragma unroll
    for (int m = 0; m < 4; ++m)
#pragma unroll
        for (int n = 0; n < 4; ++n) {
            int rrow = row0 + wm * 64 + m * 16 + g * 4;
            int ccol = col0 + wn * 64 + n * 16 + c16;
            float bv = bias[ccol];
#pragma unroll
            for (int i = 0; i < 4; ++i) {
                float v = acc[m][n][i] + bv;
                if (EPI == EPI_GELU) v = 0.5f * v * (1.f + erff(v * 0.70710678118f));
                if (EPI == EPI_RES) v += res[(size_t)(rrow + i) * N + ccol];
                if (BF16OUT)
                    ((short*)Cv)[(size_t)(rrow + i) * N + ccol] = f2bf(v);
                else
                    ((float*)Cv)[(size_t)(rrow + i) * N + ccol] = v;
            }
        }
}

// ---------------- fused MFMA flash attention, materialized bias ----------------
// Block: 256 thr (4 waves), QBLK=64 (wave w owns q-rows w*16..+15), KBLK=64.
// Static-max softmax; bias read coalesced from biasT[h][q][k] (bf16).
__global__ __launch_bounds__(256, 2) void attn_mfma(
    const short* __restrict__ qkv,
    const ushort* __restrict__ biasT,
    short* __restrict__ attn_o) {
    __shared__ short Ks[64 * 64];     // XOR-seg swizzled (by row&7)
    __shared__ short Vt[64 * 72];     // V^T [d][k], k-chunk XOR-swizzled by d>>3
    __shared__ short Pb[4][16 * 72];  // per-wave P, k-chunk XOR-swizzled by q>>2

    int tid = threadIdx.x, w = tid >> 6, l = tid & 63;
    int g = l >> 4, c16 = l & 15;
    int qt = blockIdx.x & 31, bh = blockIdx.x >> 5;
    int h = bh % H_, b = bh / H_;
    int q0 = qt * 64;
    const int QS = 3 * D_;
    const short* kvbase = qkv + (size_t)b * T_ * QS;

    // Q fragments (A-operand: row = lane&15, k contiguous per group)
    bf16x8 qf[2];
    {
        int qrow = q0 + w * 16 + c16;
        const short* qp = kvbase + (size_t)qrow * QS + h * HD_;
#pragma unroll
        for (int dk = 0; dk < 2; ++dk) qf[dk] = *(const bf16x8*)(qp + dk * 32 + g * 8);
    }
    // bias row pointers for this lane's 4 C-layout q-rows
    const ushort* bptr[4];
#pragma unroll
    for (int i = 0; i < 4; ++i)
        bptr[i] = biasT + (size_t)h * T_ * T_ + (size_t)(q0 + w * 16 + g * 4 + i) * T_;

    f32x4 zero = {0.f, 0.f, 0.f, 0.f};
    f32x4 oacc[4];
#pragma unroll
    for (int nf = 0; nf < 4; ++nf) oacc[nf] = zero;
    float lsum[4] = {0.f, 0.f, 0.f, 0.f};

    for (int kb = 0; kb < T_; kb += 64) {
        // ---- bias loads for this tile (coalesced: 4x32B segments per instr) ----
        float bv[16];
#pragma unroll
        for (int nf = 0; nf < 4; ++nf)
#pragma unroll
            for (int i = 0; i < 4; ++i) {
                unsigned u = bptr[i][kb + nf * 16 + c16];
                bv[nf * 4 + i] = __builtin_bit_cast(float, u << 16);
            }
        // ---- stage K (seg-swizzled) ----
#pragma unroll
        for (int p = 0; p < 2; ++p) {
            int sidx = p * 256 + tid;
            int row = sidx >> 3, cseg = sidx & 7;
            *(bf16x8*)&Ks[row * 64 + ((cseg ^ (row & 7)) << 3)] =
                *(const bf16x8*)(kvbase + (size_t)(kb + row) * QS + D_ + h * HD_ + cseg * 8);
        }
        // ---- stage V^T with chunk swizzle: slot(k) = ((k>>3)^(d>>3))*8 + (k&7) ----
        {
            int vrow = tid >> 2, part = tid & 3;
            const short* vp = kvbase + (size_t)(kb + vrow) * QS + 2 * D_ + h * HD_ + part * 16;
            bf16x8 v0 = *(const bf16x8*)(vp);
            bf16x8 v1 = *(const bf16x8*)(vp + 8);
            int kchunk = vrow >> 3, kpos = vrow & 7;
#pragma unroll
            for (int j = 0; j < 8; ++j) {
                int d = part * 16 + j;
                Vt[d * 72 + (((kchunk ^ (d >> 3)) & 7) << 3) + kpos] = v0[j];
            }
#pragma unroll
            for (int j = 0; j < 8; ++j) {
                int d = part * 16 + 8 + j;
                Vt[d * 72 + (((kchunk ^ (d >> 3)) & 7) << 3) + kpos] = v1[j];
            }
        }
        __syncthreads();

        // ---- QK^T ----
        f32x4 sac[4];
#pragma unroll
        for (int nf = 0; nf < 4; ++nf) sac[nf] = zero;
#pragma unroll
        for (int dk = 0; dk < 2; ++dk) {
#pragma unroll
            for (int nf = 0; nf < 4; ++nf) {
                int r = nf * 16 + c16;
                bf16x8 kf = *(const bf16x8*)&Ks[r * 64 + (((dk * 4 + g) ^ (r & 7)) << 3)];
                sac[nf] = __builtin_amdgcn_mfma_f32_16x16x32_bf16(qf[dk], kf, sac[nf], 0, 0, 0);
            }
        }

        // ---- static-max softmax: p = exp(s*scale + bias), per-lane partial sum ----
        float pp[4][4];
#pragma unroll
        for (int nf = 0; nf < 4; ++nf)
#pragma unroll
            for (int i = 0; i < 4; ++i) {
                float e = __expf(fmaf(sac[nf][i], 0.125f, bv[nf * 4 + i]));
                pp[nf][i] = e;
                lsum[i] += e;
            }
        // ---- P -> wave-private LDS (chunk-swizzled by g) ----
        short* pbw = &Pb[w][0];
#pragma unroll
        for (int nf = 0; nf < 4; ++nf) {
            int chunkbase = nf * 2 + (c16 >> 3);
            int kpos = c16 & 7;
#pragma unroll
            for (int i = 0; i < 4; ++i)
                pbw[(g * 4 + i) * 72 + (((chunkbase ^ g) & 7) << 3) + kpos] = f2bf(pp[nf][i]);
        }
        // ---- PV ----
#pragma unroll
        for (int dk = 0; dk < 2; ++dk) {
            bf16x8 pa = *(const bf16x8*)&pbw[c16 * 72 + (((dk * 4 + g) ^ (c16 >> 2)) & 7) * 8];
#pragma unroll
            for (int nf = 0; nf < 4; ++nf) {
                int d = nf * 16 + c16;
                bf16x8 vb = *(const bf16x8*)&Vt[d * 72 + (((dk * 4 + g) ^ (d >> 3)) & 7) * 8];
                oacc[nf] = __builtin_amdgcn_mfma_f32_16x16x32_bf16(pa, vb, oacc[nf], 0, 0, 0);
            }
        }
        __syncthreads();
    }

    // ---- one-time denominator reduction across the 16 lanes of each row ----
#pragma unroll
    for (int i = 0; i < 4; ++i) {
#pragma unroll
        for (int off = 1; off < 16; off <<= 1) lsum[i] += __shfl_xor(lsum[i], off, 64);
    }

    // ---- finalize ----
#pragma unroll
    for (int nf = 0; nf < 4; ++nf)
#pragma unroll
        for (int i = 0; i < 4; ++i) {
            float o = oacc[nf][i] / lsum[i];
            int qq = q0 + w * 16 + g * 4 + i;
            attn_o[(size_t)(b * T_ + qq) * D_ + h * HD_ + nf * 16 + c16] = f2bf(o);
        }
}

// ---------------- launcher ----------------
extern "C" void kernel_launch(void* const* d_in, const int* in_sizes, int n_in,
                              void* d_out, int out_size, void* d_ws, size_t ws_size,
                              hipStream_t stream) {
    const float* x = (const float*)d_in[0];
    const int* rowp = (const int*)d_in[1];
    const int* colp = (const int*)d_in[2];
    const int* drowp = (const int*)d_in[3];
    const int* dcolp = (const int*)d_in[4];
    const int* didp = (const int*)d_in[5];
    // d_in[6] = is_sep (bool) — unused: is_sep <=> demo_id < 0 by construction
    const float* ln1_w = (const float*)d_in[7];
    const float* ln1_b = (const float*)d_in[8];
    const float* ln2_w = (const float*)d_in[9];
    const float* ln2_b = (const float*)d_in[10];
    const float* qkv_w = (const float*)d_in[11];
    const float* qkv_b = (const float*)d_in[12];
    const float* proj_w = (const float*)d_in[13];
    const float* proj_b = (const float*)d_in[14];
    const float* ff1_w = (const float*)d_in[15];
    const float* ff1_b = (const float*)d_in[16];
    const float* ff2_w = (const float*)d_in[17];
    const float* ff2_b = (const float*)d_in[18];
    const float* rel_emb = (const float*)d_in[19];
    const float* demo_emb = (const float*)d_in[20];
    float* out = (float*)d_out;

    const int M = B_ * T_;  // 4096
    char* p = (char*)d_ws;
    short* h1 = (short*)p;     p += (size_t)M * D_ * 2;          //  6.29 MB
    short* qkvb = (short*)p;   p += (size_t)M * 3 * D_ * 2;      // 18.87 MB
    short* attn_o = (short*)p; p += (size_t)M * D_ * 2;          //  6.29 MB
    short* qkvt = (short*)p;   p += (size_t)(3 * D_) * D_ * 2;   //  3.54 MB
    short* projt = (short*)p;  p += (size_t)D_ * D_ * 2;         //  1.18 MB
    short* ff1t = (short*)p;   p += (size_t)FF_ * D_ * 2;        //  4.72 MB
    short* ff2t = (short*)p;   p += (size_t)D_ * FF_ * 2;        //  4.72 MB
    // overlay region: biasT (96 MB, live until attention) aliases
    // x2 + h2 + ffact (all written only AFTER attention) + extension.
    float* x2 = (float*)p;                                       // 12.58 MB
    short* h2 = (short*)(p + (size_t)M * D_ * 4);                //  6.29 MB
    short* ffact = (short*)(p + (size_t)M * D_ * 4 + (size_t)M * D_ * 2);  // 25.17 MB
    ushort* biasT = (ushort*)p;  // needs 12*2048*2048*2 = 100.66 MB from here

    // ---- precompute ----
    bias_build<<<dim3(T_ / 64, T_ / 16), 256, 0, stream>>>(
        rowp, colp, drowp, dcolp, didp, rel_emb, demo_emb, biasT);
    tcast_kernel<<<dim3(3 * D_ / 32, D_ / 32), 256, 0, stream>>>(qkv_w, qkvt, D_, 3 * D_);
    tcast_kernel<<<dim3(D_ / 32, D_ / 32), 256, 0, stream>>>(proj_w, projt, D_, D_);
    tcast_kernel<<<dim3(FF_ / 32, D_ / 32), 256, 0, stream>>>(ff1_w, ff1t, D_, FF_);
    tcast_kernel<<<dim3(D_ / 32, FF_ / 32), 256, 0, stream>>>(ff2_w, ff2t, FF_, D_);

    // ---- main pipeline ----
    ln_bf16_kernel<<<dim3(M / 4), 256, 0, stream>>>(x, ln1_w, ln1_b, h1);

    gemm_bf16<EPI_NONE, 1><<<dim3(3 * D_ / 128, M / 128), 256, 0, stream>>>(
        h1, qkvt, qkv_b, nullptr, qkvb, M, 3 * D_, D_);

    attn_mfma<<<dim3(B_ * H_ * (T_ / 64)), 256, 0, stream>>>(qkvb, biasT, attn_o);

    gemm_bf16<EPI_RES, 0><<<dim3(D_ / 128, M / 128), 256, 0, stream>>>(
        attn_o, projt, proj_b, x, x2, M, D_, D_);

    ln_bf16_kernel<<<dim3(M / 4), 256, 0, stream>>>(x2, ln2_w, ln2_b, h2);

    gemm_bf16<EPI_GELU, 1><<<dim3(FF_ / 128, M / 128), 256, 0, stream>>>(
        h2, ff1t, ff1_b, nullptr, ffact, M, FF_, D_);

    gemm_bf16<EPI_RES, 0><<<dim3(D_ / 128, M / 128), 256, 0, stream>>>(
        ffact, ff2t, ff2_b, x2, out, M, D_, FF_);
}

// Round 8
// 266.614 us; speedup vs baseline: 2.0888x; 1.0394x over previous
//
#include <hip/hip_runtime.h>
#include <hip/hip_bf16.h>
#include <math.h>

#define G_ 32
#define H_ 12
#define D_ 768
#define HD_ 64
#define FF_ 3072
#define B_ 2
#define T_ 2048
#define SPAN_ 63
#define SPANC_ 129
#define EPSF 1e-5f

typedef short bf16x8 __attribute__((ext_vector_type(8)));
typedef short short4v __attribute__((ext_vector_type(4)));
typedef float f32x4 __attribute__((ext_vector_type(4)));

__device__ __forceinline__ short f2bf(float f) {
    unsigned u = __builtin_bit_cast(unsigned, f);
    u = u + 0x7FFFu + ((u >> 16) & 1u);
    return (short)(u >> 16);
}

// async global->LDS, 16B per lane; LDS dest = wave-uniform base + lane*16
__device__ __forceinline__ void gl_lds16(const void* g, void* l) {
    __builtin_amdgcn_global_load_lds(
        (const __attribute__((address_space(1))) unsigned int*)g,
        (__attribute__((address_space(3))) unsigned int*)l, 16, 0, 0);
}

// ---------------- LayerNorm (f32 in -> bf16 out): one wave per row ----------------
__global__ __launch_bounds__(256) void ln_bf16_kernel(const float* __restrict__ x,
                                                      const float* __restrict__ w,
                                                      const float* __restrict__ b,
                                                      short* __restrict__ out) {
    int wv = threadIdx.x >> 6;
    int lane = threadIdx.x & 63;
    int rowi = blockIdx.x * 4 + wv;
    const float* xr = x + (size_t)rowi * D_;
    float vals[12];
    float s = 0.f;
#pragma unroll
    for (int i = 0; i < 12; ++i) { vals[i] = xr[lane + i * 64]; s += vals[i]; }
#pragma unroll
    for (int off = 32; off > 0; off >>= 1) s += __shfl_xor(s, off, 64);
    float mean = s * (1.0f / D_);
    float vs = 0.f;
#pragma unroll
    for (int i = 0; i < 12; ++i) { float d = vals[i] - mean; vs += d * d; }
#pragma unroll
    for (int off = 32; off > 0; off >>= 1) vs += __shfl_xor(vs, off, 64);
    float rstd = rsqrtf(vs * (1.0f / D_) + EPSF);
    short* outr = out + (size_t)rowi * D_;
#pragma unroll
    for (int i = 0; i < 12; ++i) {
        int c = lane + i * 64;
        outr[c] = f2bf((vals[i] - mean) * rstd * w[c] + b[c]);
    }
}

// ---------------- transpose-cast: W [K][N] f32 -> Wt [N][K] bf16 ----------------
__global__ __launch_bounds__(256) void tcast_kernel(const float* __restrict__ W,
                                                    short* __restrict__ Wt,
                                                    int K, int N) {
    __shared__ float t[32][33];
    int n0 = blockIdx.x * 32, k0 = blockIdx.y * 32;
    int tid = threadIdx.x;
    int r = tid >> 3, c4 = (tid & 7) * 4;
    float4 v = *(const float4*)(W + (size_t)(k0 + r) * N + n0 + c4);
    t[r][c4 + 0] = v.x; t[r][c4 + 1] = v.y; t[r][c4 + 2] = v.z; t[r][c4 + 3] = v.w;
    __syncthreads();
    short4v o;
    o[0] = f2bf(t[c4 + 0][r]); o[1] = f2bf(t[c4 + 1][r]);
    o[2] = f2bf(t[c4 + 2][r]); o[3] = f2bf(t[c4 + 3][r]);
    *(short4v*)(Wt + (size_t)(n0 + r) * K + k0 + c4) = o;
}

// ---------------- bias materialization: biasT[h][q][k] bf16 ----------------
__global__ __launch_bounds__(256) void bias_build(
    const int* __restrict__ rowp, const int* __restrict__ colp,
    const int* __restrict__ drowp, const int* __restrict__ dcolp,
    const int* __restrict__ didp,
    const float* __restrict__ rel_emb, const float* __restrict__ demo_emb,
    ushort* __restrict__ biasT) {
    __shared__ ushort patch[12][16][72];
    int k0 = blockIdx.x * 64, q0 = blockIdx.y * 16;
    int tid = threadIdx.x;
    int qi = tid >> 4, kq = (tid & 15) * 4;
    int q = q0 + qi;
    int idq = didp[q];
    int rq = rowp[q], cq = colp[q], drq = drowp[q], dcq = dcolp[q];
#pragma unroll
    for (int j = 0; j < 4; ++j) {
        int k = k0 + kq + j;
        int idk = didp[k];
        float4 v0 = {0.f, 0.f, 0.f, 0.f}, v1 = v0, v2 = v0;
        if (idq >= 0 && idk >= 0) {
            int dr = min(max(rq - rowp[k], -(G_ - 1)), G_ - 1) + (G_ - 1);
            int dc = min(max(cq - colp[k], -(G_ - 1)), G_ - 1) + (G_ - 1);
            const float* rp = rel_emb + (size_t)(dr * SPAN_ + dc) * 12;
            v0 = *(const float4*)rp;
            v1 = *(const float4*)(rp + 4);
            v2 = *(const float4*)(rp + 8);
            if (idq == idk) {
                int ddr = min(max(drq - drowp[k], -(G_ - 1)), G_ - 1) + (G_ - 1);
                int ddc = min(max(dcq - dcolp[k], -2 * G_), 2 * G_) + 2 * G_;
                const float* dp = demo_emb + (size_t)(ddr * SPANC_ + ddc) * 12;
                float4 w0 = *(const float4*)dp;
                float4 w1 = *(const float4*)(dp + 4);
                float4 w2 = *(const float4*)(dp + 8);
                v0.x += w0.x; v0.y += w0.y; v0.z += w0.z; v0.w += w0.w;
                v1.x += w1.x; v1.y += w1.y; v1.z += w1.z; v1.w += w1.w;
                v2.x += w2.x; v2.y += w2.y; v2.z += w2.z; v2.w += w2.w;
            }
        }
        float bv[12] = {v0.x, v0.y, v0.z, v0.w, v1.x, v1.y, v1.z, v1.w,
                        v2.x, v2.y, v2.z, v2.w};
        int kl = kq + j;
#pragma unroll
        for (int h = 0; h < 12; ++h) patch[h][qi][kl] = (ushort)f2bf(bv[h]);
    }
    __syncthreads();
    for (int c = tid; c < 1536; c += 256) {
        int rowid = c >> 3, off = (c & 7) * 8;
        int h = rowid >> 4, q2 = rowid & 15;
        *(bf16x8*)(biasT + (size_t)h * T_ * T_ + (size_t)(q0 + q2) * T_ + k0 + off) =
            *(const bf16x8*)&patch[h][q2][off];
    }
}

// ---------------- bf16 MFMA GEMM: C = A[M][K] * Bt[N][K]^T ----------------
// 128x128 tile, BK=64, 4 waves (2x2). Staging via global_load_lds width=16:
// linear LDS dest, inverse-swizzled global source, XOR-swizzled ds_read (m201 #21).
enum { EPI_NONE = 0, EPI_RES = 1, EPI_GELU = 2 };

template <int EPI, int BF16OUT>
__global__ __launch_bounds__(256, 2) void gemm_bf16(const short* __restrict__ A,
                                                    const short* __restrict__ Bt,
                                                    const float* __restrict__ bias,
                                                    const float* __restrict__ res,
                                                    void* __restrict__ Cv,
                                                    int M, int N, int K) {
    __shared__ short As[128 * 64];
    __shared__ short Bs[128 * 64];
    int tid = threadIdx.x;
    int l = tid & 63;
    int w = tid >> 6;
    int wm = w >> 1, wn = w & 1;
    int row0 = blockIdx.y * 128, col0 = blockIdx.x * 128;
    int g = l >> 4, c16 = l & 15;
    f32x4 zero = {0.f, 0.f, 0.f, 0.f};
    f32x4 acc[4][4];
#pragma unroll
    for (int m = 0; m < 4; ++m)
#pragma unroll
        for (int n = 0; n < 4; ++n) acc[m][n] = zero;

    // staging geometry: wave w covers rows w*32..w*32+31 (4 instrs x 8 rows);
    // lane l: row_in_instr = l>>3, source seg = (l&7) ^ (row&7)  [inverse swizzle]
    int srow = w * 32 + (l >> 3);           // rows for inst 0; inst i adds 8
    int sseg0 = (l & 7);

    for (int k0 = 0; k0 < K; k0 += 64) {
#pragma unroll
        for (int inst = 0; inst < 4; ++inst) {
            int arow = srow + inst * 8;
            int seg = sseg0 ^ (arow & 7);
            gl_lds16(A + (size_t)(row0 + arow) * K + k0 + seg * 8,
                     &As[(w * 32 + inst * 8) * 64]);
            gl_lds16(Bt + (size_t)(col0 + arow) * K + k0 + seg * 8,
                     &Bs[(w * 32 + inst * 8) * 64]);
        }
        __syncthreads();
#pragma unroll
        for (int dk = 0; dk < 2; ++dk) {
            bf16x8 af[4], bfr[4];
#pragma unroll
            for (int m = 0; m < 4; ++m) {
                int r = wm * 64 + m * 16 + c16;
                af[m] = *(const bf16x8*)&As[r * 64 + (((dk * 4 + g) ^ (r & 7)) << 3)];
            }
#pragma unroll
            for (int n = 0; n < 4; ++n) {
                int r = wn * 64 + n * 16 + c16;
                bfr[n] = *(const bf16x8*)&Bs[r * 64 + (((dk * 4 + g) ^ (r & 7)) << 3)];
            }
#pragma unroll
            for (int m = 0; m < 4; ++m)
#pragma unroll
                for (int n = 0; n < 4; ++n)
                    acc[m][n] = __builtin_amdgcn_mfma_f32_16x16x32_bf16(af[m], bfr[n], acc[m][n], 0, 0, 0);
        }
        __syncthreads();
    }

#pragma unroll
    for (int m = 0; m < 4; ++m)
#pragma unroll
        for (int n = 0; n < 4; ++n) {
            int rrow = row0 + wm * 64 + m * 16 + g * 4;
            int ccol = col0 + wn * 64 + n * 16 + c16;
            float bv = bias[ccol];
#pragma unroll
            for (int i = 0; i < 4; ++i) {
                float v = acc[m][n][i] + bv;
                if (EPI == EPI_GELU) v = 0.5f * v * (1.f + erff(v * 0.70710678118f));
                if (EPI == EPI_RES) v += res[(size_t)(rrow + i) * N + ccol];
                if (BF16OUT)
                    ((short*)Cv)[(size_t)(rrow + i) * N + ccol] = f2bf(v);
                else
                    ((float*)Cv)[(size_t)(rrow + i) * N + ccol] = v;
            }
        }
}

// ---------------- fused MFMA flash attention, materialized bias ----------------
// Block: 256 thr (4 waves), QBLK=64 (wave w owns q-rows w*16..+15), KBLK=64.
// Static-max softmax; bias read coalesced from biasT[h][q][k], prefetched 1 tile deep.
__global__ __launch_bounds__(256, 2) void attn_mfma(
    const short* __restrict__ qkv,
    const ushort* __restrict__ biasT,
    short* __restrict__ attn_o) {
    __shared__ short Ks[64 * 64];     // XOR-seg swizzled (by row&7)
    __shared__ short Vt[64 * 72];     // V^T [d][k], k-chunk XOR-swizzled by d>>3
    __shared__ short Pb[4][16 * 72];  // per-wave P, k-chunk XOR-swizzled by q>>2

    int tid = threadIdx.x, w = tid >> 6, l = tid & 63;
    int g = l >> 4, c16 = l & 15;
    int qt = blockIdx.x & 31, bh = blockIdx.x >> 5;
    int h = bh % H_, b = bh / H_;
    int q0 = qt * 64;
    const int QS = 3 * D_;
    const short* kvbase = qkv + (size_t)b * T_ * QS;

    // Q fragments (A-operand: row = lane&15, k contiguous per group)
    bf16x8 qf[2];
    {
        int qrow = q0 + w * 16 + c16;
        const short* qp = kvbase + (size_t)qrow * QS + h * HD_;
#pragma unroll
        for (int dk = 0; dk < 2; ++dk) qf[dk] = *(const bf16x8*)(qp + dk * 32 + g * 8);
    }
    // bias row pointers for this lane's 4 C-layout q-rows
    const ushort* bptr[4];
#pragma unroll
    for (int i = 0; i < 4; ++i)
        bptr[i] = biasT + (size_t)h * T_ * T_ + (size_t)(q0 + w * 16 + g * 4 + i) * T_;

    f32x4 zero = {0.f, 0.f, 0.f, 0.f};
    f32x4 oacc[4];
#pragma unroll
    for (int nf = 0; nf < 4; ++nf) oacc[nf] = zero;
    float lsum[4] = {0.f, 0.f, 0.f, 0.f};

    // 1-deep bias prefetch (raw ushorts; j = nf*4 + i)
    unsigned bvu[16];
#pragma unroll
    for (int nf = 0; nf < 4; ++nf)
#pragma unroll
        for (int i = 0; i < 4; ++i)
            bvu[nf * 4 + i] = bptr[i][nf * 16 + c16];

    for (int kb = 0; kb < T_; kb += 64) {
        // ---- prefetch next tile's bias ----
        unsigned bvn[16];
        {
            int kbn = (kb + 64) & (T_ - 1);
#pragma unroll
            for (int nf = 0; nf < 4; ++nf)
#pragma unroll
                for (int i = 0; i < 4; ++i)
                    bvn[nf * 4 + i] = bptr[i][kbn + nf * 16 + c16];
        }
        // ---- stage K (seg-swizzled) ----
#pragma unroll
        for (int p = 0; p < 2; ++p) {
            int sidx = p * 256 + tid;
            int row = sidx >> 3, cseg = sidx & 7;
            *(bf16x8*)&Ks[row * 64 + ((cseg ^ (row & 7)) << 3)] =
                *(const bf16x8*)(kvbase + (size_t)(kb + row) * QS + D_ + h * HD_ + cseg * 8);
        }
        // ---- stage V^T with chunk swizzle: slot(k) = ((k>>3)^(d>>3))*8 + (k&7) ----
        {
            int vrow = tid >> 2, part = tid & 3;
            const short* vp = kvbase + (size_t)(kb + vrow) * QS + 2 * D_ + h * HD_ + part * 16;
            bf16x8 v0 = *(const bf16x8*)(vp);
            bf16x8 v1 = *(const bf16x8*)(vp + 8);
            int kchunk = vrow >> 3, kpos = vrow & 7;
#pragma unroll
            for (int j = 0; j < 8; ++j) {
                int d = part * 16 + j;
                Vt[d * 72 + (((kchunk ^ (d >> 3)) & 7) << 3) + kpos] = v0[j];
            }
#pragma unroll
            for (int j = 0; j < 8; ++j) {
                int d = part * 16 + 8 + j;
                Vt[d * 72 + (((kchunk ^ (d >> 3)) & 7) << 3) + kpos] = v1[j];
            }
        }
        __syncthreads();

        // ---- QK^T ----
        f32x4 sac[4];
#pragma unroll
        for (int nf = 0; nf < 4; ++nf) sac[nf] = zero;
#pragma unroll
        for (int dk = 0; dk < 2; ++dk) {
#pragma unroll
            for (int nf = 0; nf < 4; ++nf) {
                int r = nf * 16 + c16;
                bf16x8 kf = *(const bf16x8*)&Ks[r * 64 + (((dk * 4 + g) ^ (r & 7)) << 3)];
                sac[nf] = __builtin_amdgcn_mfma_f32_16x16x32_bf16(qf[dk], kf, sac[nf], 0, 0, 0);
            }
        }

        // ---- static-max softmax: p = exp(s*scale + bias), per-lane partial sum ----
        float pp[4][4];
#pragma unroll
        for (int nf = 0; nf < 4; ++nf)
#pragma unroll
            for (int i = 0; i < 4; ++i) {
                float bvf = __builtin_bit_cast(float, bvu[nf * 4 + i] << 16);
                float e = __expf(fmaf(sac[nf][i], 0.125f, bvf));
                pp[nf][i] = e;
                lsum[i] += e;
            }
        // ---- P -> wave-private LDS (chunk-swizzled by g) ----
        short* pbw = &Pb[w][0];
#pragma unroll
        for (int nf = 0; nf < 4; ++nf) {
            int chunkbase = nf * 2 + (c16 >> 3);
            int kpos = c16 & 7;
#pragma unroll
            for (int i = 0; i < 4; ++i)
                pbw[(g * 4 + i) * 72 + (((chunkbase ^ g) & 7) << 3) + kpos] = f2bf(pp[nf][i]);
        }
        // ---- PV ----
#pragma unroll
        for (int dk = 0; dk < 2; ++dk) {
            bf16x8 pa = *(const bf16x8*)&pbw[c16 * 72 + (((dk * 4 + g) ^ (c16 >> 2)) & 7) * 8];
#pragma unroll
            for (int nf = 0; nf < 4; ++nf) {
                int d = nf * 16 + c16;
                bf16x8 vb = *(const bf16x8*)&Vt[d * 72 + (((dk * 4 + g) ^ (d >> 3)) & 7) * 8];
                oacc[nf] = __builtin_amdgcn_mfma_f32_16x16x32_bf16(pa, vb, oacc[nf], 0, 0, 0);
            }
        }
#pragma unroll
        for (int j = 0; j < 16; ++j) bvu[j] = bvn[j];
        __syncthreads();
    }

    // ---- one-time denominator reduction across the 16 lanes of each row ----
#pragma unroll
    for (int i = 0; i < 4; ++i) {
#pragma unroll
        for (int off = 1; off < 16; off <<= 1) lsum[i] += __shfl_xor(lsum[i], off, 64);
    }

    // ---- finalize ----
#pragma unroll
    for (int nf = 0; nf < 4; ++nf)
#pragma unroll
        for (int i = 0; i < 4; ++i) {
            float o = oacc[nf][i] / lsum[i];
            int qq = q0 + w * 16 + g * 4 + i;
            attn_o[(size_t)(b * T_ + qq) * D_ + h * HD_ + nf * 16 + c16] = f2bf(o);
        }
}

// ---------------- launcher ----------------
extern "C" void kernel_launch(void* const* d_in, const int* in_sizes, int n_in,
                              void* d_out, int out_size, void* d_ws, size_t ws_size,
                              hipStream_t stream) {
    const float* x = (const float*)d_in[0];
    const int* rowp = (const int*)d_in[1];
    const int* colp = (const int*)d_in[2];
    const int* drowp = (const int*)d_in[3];
    const int* dcolp = (const int*)d_in[4];
    const int* didp = (const int*)d_in[5];
    // d_in[6] = is_sep (bool) — unused: is_sep <=> demo_id < 0 by construction
    const float* ln1_w = (const float*)d_in[7];
    const float* ln1_b = (const float*)d_in[8];
    const float* ln2_w = (const float*)d_in[9];
    const float* ln2_b = (const float*)d_in[10];
    const float* qkv_w = (const float*)d_in[11];
    const float* qkv_b = (const float*)d_in[12];
    const float* proj_w = (const float*)d_in[13];
    const float* proj_b = (const float*)d_in[14];
    const float* ff1_w = (const float*)d_in[15];
    const float* ff1_b = (const float*)d_in[16];
    const float* ff2_w = (const float*)d_in[17];
    const float* ff2_b = (const float*)d_in[18];
    const float* rel_emb = (const float*)d_in[19];
    const float* demo_emb = (const float*)d_in[20];
    float* out = (float*)d_out;

    const int M = B_ * T_;  // 4096
    char* p = (char*)d_ws;
    short* h1 = (short*)p;     p += (size_t)M * D_ * 2;          //  6.29 MB
    short* qkvb = (short*)p;   p += (size_t)M * 3 * D_ * 2;      // 18.87 MB
    short* attn_o = (short*)p; p += (size_t)M * D_ * 2;          //  6.29 MB
    short* qkvt = (short*)p;   p += (size_t)(3 * D_) * D_ * 2;   //  3.54 MB
    short* projt = (short*)p;  p += (size_t)D_ * D_ * 2;         //  1.18 MB
    short* ff1t = (short*)p;   p += (size_t)FF_ * D_ * 2;        //  4.72 MB
    short* ff2t = (short*)p;   p += (size_t)D_ * FF_ * 2;        //  4.72 MB
    // overlay region: biasT (100.7 MB, live until attention) aliases
    // x2 + h2 + ffact (all written only AFTER attention) + extension.
    float* x2 = (float*)p;                                       // 12.58 MB
    short* h2 = (short*)(p + (size_t)M * D_ * 4);                //  6.29 MB
    short* ffact = (short*)(p + (size_t)M * D_ * 4 + (size_t)M * D_ * 2);  // 25.17 MB
    ushort* biasT = (ushort*)p;  // 12*2048*2048*2 = 100.66 MB from here

    // ---- precompute ----
    bias_build<<<dim3(T_ / 64, T_ / 16), 256, 0, stream>>>(
        rowp, colp, drowp, dcolp, didp, rel_emb, demo_emb, biasT);
    tcast_kernel<<<dim3(3 * D_ / 32, D_ / 32), 256, 0, stream>>>(qkv_w, qkvt, D_, 3 * D_);
    tcast_kernel<<<dim3(D_ / 32, D_ / 32), 256, 0, stream>>>(proj_w, projt, D_, D_);
    tcast_kernel<<<dim3(FF_ / 32, D_ / 32), 256, 0, stream>>>(ff1_w, ff1t, D_, FF_);
    tcast_kernel<<<dim3(D_ / 32, FF_ / 32), 256, 0, stream>>>(ff2_w, ff2t, FF_, D_);

    // ---- main pipeline ----
    ln_bf16_kernel<<<dim3(M / 4), 256, 0, stream>>>(x, ln1_w, ln1_b, h1);

    gemm_bf16<EPI_NONE, 1><<<dim3(3 * D_ / 128, M / 128), 256, 0, stream>>>(
        h1, qkvt, qkv_b, nullptr, qkvb, M, 3 * D_, D_);

    attn_mfma<<<dim3(B_ * H_ * (T_ / 64)), 256, 0, stream>>>(qkvb, biasT, attn_o);

    gemm_bf16<EPI_RES, 0><<<dim3(D_ / 128, M / 128), 256, 0, stream>>>(
        attn_o, projt, proj_b, x, x2, M, D_, D_);

    ln_bf16_kernel<<<dim3(M / 4), 256, 0, stream>>>(x2, ln2_w, ln2_b, h2);

    gemm_bf16<EPI_GELU, 1><<<dim3(FF_ / 128, M / 128), 256, 0, stream>>>(
        h2, ff1t, ff1_b, nullptr, ffact, M, FF_, D_);

    gemm_bf16<EPI_RES, 0><<<dim3(D_ / 128, M / 128), 256, 0, stream>>>(
        ffact, ff2t, ff2_b, x2, out, M, D_, FF_);
}

// Round 9
// 262.933 us; speedup vs baseline: 2.1180x; 1.0140x over previous
//
#include <hip/hip_runtime.h>
#include <hip/hip_bf16.h>
#include <math.h>

#define G_ 32
#define H_ 12
#define D_ 768
#define HD_ 64
#define FF_ 3072
#define B_ 2
#define T_ 2048
#define SPAN_ 63
#define SPANC_ 129
#define EPSF 1e-5f

typedef short bf16x8 __attribute__((ext_vector_type(8)));
typedef short short4v __attribute__((ext_vector_type(4)));
typedef float f32x4 __attribute__((ext_vector_type(4)));

__device__ __forceinline__ short f2bf(float f) {
    unsigned u = __builtin_bit_cast(unsigned, f);
    u = u + 0x7FFFu + ((u >> 16) & 1u);
    return (short)(u >> 16);
}

// async global->LDS, 16B per lane; LDS dest = wave-uniform base + lane*16
__device__ __forceinline__ void gl_lds16(const void* g, void* l) {
    __builtin_amdgcn_global_load_lds(
        (const __attribute__((address_space(1))) unsigned int*)g,
        (__attribute__((address_space(3))) unsigned int*)l, 16, 0, 0);
}

// ---------------- LayerNorm (f32 in -> bf16 out): one wave per row ----------------
__global__ __launch_bounds__(256) void ln_bf16_kernel(const float* __restrict__ x,
                                                      const float* __restrict__ w,
                                                      const float* __restrict__ b,
                                                      short* __restrict__ out) {
    int wv = threadIdx.x >> 6;
    int lane = threadIdx.x & 63;
    int rowi = blockIdx.x * 4 + wv;
    const float* xr = x + (size_t)rowi * D_;
    float vals[12];
    float s = 0.f;
#pragma unroll
    for (int i = 0; i < 12; ++i) { vals[i] = xr[lane + i * 64]; s += vals[i]; }
#pragma unroll
    for (int off = 32; off > 0; off >>= 1) s += __shfl_xor(s, off, 64);
    float mean = s * (1.0f / D_);
    float vs = 0.f;
#pragma unroll
    for (int i = 0; i < 12; ++i) { float d = vals[i] - mean; vs += d * d; }
#pragma unroll
    for (int off = 32; off > 0; off >>= 1) vs += __shfl_xor(vs, off, 64);
    float rstd = rsqrtf(vs * (1.0f / D_) + EPSF);
    short* outr = out + (size_t)rowi * D_;
#pragma unroll
    for (int i = 0; i < 12; ++i) {
        int c = lane + i * 64;
        outr[c] = f2bf((vals[i] - mean) * rstd * w[c] + b[c]);
    }
}

// ---------------- transpose-cast: W [K][N] f32 -> Wt [N][K] bf16 ----------------
__global__ __launch_bounds__(256) void tcast_kernel(const float* __restrict__ W,
                                                    short* __restrict__ Wt,
                                                    int K, int N) {
    __shared__ float t[32][33];
    int n0 = blockIdx.x * 32, k0 = blockIdx.y * 32;
    int tid = threadIdx.x;
    int r = tid >> 3, c4 = (tid & 7) * 4;
    float4 v = *(const float4*)(W + (size_t)(k0 + r) * N + n0 + c4);
    t[r][c4 + 0] = v.x; t[r][c4 + 1] = v.y; t[r][c4 + 2] = v.z; t[r][c4 + 3] = v.w;
    __syncthreads();
    short4v o;
    o[0] = f2bf(t[c4 + 0][r]); o[1] = f2bf(t[c4 + 1][r]);
    o[2] = f2bf(t[c4 + 2][r]); o[3] = f2bf(t[c4 + 3][r]);
    *(short4v*)(Wt + (size_t)(n0 + r) * K + k0 + c4) = o;
}

// ---------------- bias materialization: biasT[h][q][k] bf16 ----------------
__global__ __launch_bounds__(256) void bias_build(
    const int* __restrict__ rowp, const int* __restrict__ colp,
    const int* __restrict__ drowp, const int* __restrict__ dcolp,
    const int* __restrict__ didp,
    const float* __restrict__ rel_emb, const float* __restrict__ demo_emb,
    ushort* __restrict__ biasT) {
    __shared__ ushort patch[12][16][72];
    int k0 = blockIdx.x * 64, q0 = blockIdx.y * 16;
    int tid = threadIdx.x;
    int qi = tid >> 4, kq = (tid & 15) * 4;
    int q = q0 + qi;
    int idq = didp[q];
    int rq = rowp[q], cq = colp[q], drq = drowp[q], dcq = dcolp[q];
#pragma unroll
    for (int j = 0; j < 4; ++j) {
        int k = k0 + kq + j;
        int idk = didp[k];
        float4 v0 = {0.f, 0.f, 0.f, 0.f}, v1 = v0, v2 = v0;
        if (idq >= 0 && idk >= 0) {
            int dr = min(max(rq - rowp[k], -(G_ - 1)), G_ - 1) + (G_ - 1);
            int dc = min(max(cq - colp[k], -(G_ - 1)), G_ - 1) + (G_ - 1);
            const float* rp = rel_emb + (size_t)(dr * SPAN_ + dc) * 12;
            v0 = *(const float4*)rp;
            v1 = *(const float4*)(rp + 4);
            v2 = *(const float4*)(rp + 8);
            if (idq == idk) {
                int ddr = min(max(drq - drowp[k], -(G_ - 1)), G_ - 1) + (G_ - 1);
                int ddc = min(max(dcq - dcolp[k], -2 * G_), 2 * G_) + 2 * G_;
                const float* dp = demo_emb + (size_t)(ddr * SPANC_ + ddc) * 12;
                float4 w0 = *(const float4*)dp;
                float4 w1 = *(const float4*)(dp + 4);
                float4 w2 = *(const float4*)(dp + 8);
                v0.x += w0.x; v0.y += w0.y; v0.z += w0.z; v0.w += w0.w;
                v1.x += w1.x; v1.y += w1.y; v1.z += w1.z; v1.w += w1.w;
                v2.x += w2.x; v2.y += w2.y; v2.z += w2.z; v2.w += w2.w;
            }
        }
        float bv[12] = {v0.x, v0.y, v0.z, v0.w, v1.x, v1.y, v1.z, v1.w,
                        v2.x, v2.y, v2.z, v2.w};
        int kl = kq + j;
#pragma unroll
        for (int h = 0; h < 12; ++h) patch[h][qi][kl] = (ushort)f2bf(bv[h]);
    }
    __syncthreads();
    for (int c = tid; c < 1536; c += 256) {
        int rowid = c >> 3, off = (c & 7) * 8;
        int h = rowid >> 4, q2 = rowid & 15;
        *(bf16x8*)(biasT + (size_t)h * T_ * T_ + (size_t)(q0 + q2) * T_ + k0 + off) =
            *(const bf16x8*)&patch[h][q2][off];
    }
}

// ---------------- bf16 MFMA GEMM: C = A[M][K] * Bt[N][K]^T ----------------
enum { EPI_NONE = 0, EPI_RES = 1, EPI_GELU = 2 };

template <int EPI, int BF16OUT>
__global__ __launch_bounds__(256, 2) void gemm_bf16(const short* __restrict__ A,
                                                    const short* __restrict__ Bt,
                                                    const float* __restrict__ bias,
                                                    const float* __restrict__ res,
                                                    void* __restrict__ Cv,
                                                    int M, int N, int K) {
    __shared__ short As[128 * 64];
    __shared__ short Bs[128 * 64];
    int tid = threadIdx.x;
    int l = tid & 63;
    int w = tid >> 6;
    int wm = w >> 1, wn = w & 1;
    int row0 = blockIdx.y * 128, col0 = blockIdx.x * 128;
    int g = l >> 4, c16 = l & 15;
    f32x4 zero = {0.f, 0.f, 0.f, 0.f};
    f32x4 acc[4][4];
#pragma unroll
    for (int m = 0; m < 4; ++m)
#pragma unroll
        for (int n = 0; n < 4; ++n) acc[m][n] = zero;

    int srow = w * 32 + (l >> 3);
    int sseg0 = (l & 7);

    for (int k0 = 0; k0 < K; k0 += 64) {
#pragma unroll
        for (int inst = 0; inst < 4; ++inst) {
            int arow = srow + inst * 8;
            int seg = sseg0 ^ (arow & 7);
            gl_lds16(A + (size_t)(row0 + arow) * K + k0 + seg * 8,
                     &As[(w * 32 + inst * 8) * 64]);
            gl_lds16(Bt + (size_t)(col0 + arow) * K + k0 + seg * 8,
                     &Bs[(w * 32 + inst * 8) * 64]);
        }
        __syncthreads();
#pragma unroll
        for (int dk = 0; dk < 2; ++dk) {
            bf16x8 af[4], bfr[4];
#pragma unroll
            for (int m = 0; m < 4; ++m) {
                int r = wm * 64 + m * 16 + c16;
                af[m] = *(const bf16x8*)&As[r * 64 + (((dk * 4 + g) ^ (r & 7)) << 3)];
            }
#pragma unroll
            for (int n = 0; n < 4; ++n) {
                int r = wn * 64 + n * 16 + c16;
                bfr[n] = *(const bf16x8*)&Bs[r * 64 + (((dk * 4 + g) ^ (r & 7)) << 3)];
            }
#pragma unroll
            for (int m = 0; m < 4; ++m)
#pragma unroll
                for (int n = 0; n < 4; ++n)
                    acc[m][n] = __builtin_amdgcn_mfma_f32_16x16x32_bf16(af[m], bfr[n], acc[m][n], 0, 0, 0);
        }
        __syncthreads();
    }

#pragma unroll
    for (int m = 0; m < 4; ++m)
#pragma unroll
        for (int n = 0; n < 4; ++n) {
            int rrow = row0 + wm * 64 + m * 16 + g * 4;
            int ccol = col0 + wn * 64 + n * 16 + c16;
            float bv = bias[ccol];
#pragma unroll
            for (int i = 0; i < 4; ++i) {
                float v = acc[m][n][i] + bv;
                if (EPI == EPI_GELU) v = 0.5f * v * (1.f + erff(v * 0.70710678118f));
                if (EPI == EPI_RES) v += res[(size_t)(rrow + i) * N + ccol];
                if (BF16OUT)
                    ((short*)Cv)[(size_t)(rrow + i) * N + ccol] = f2bf(v);
                else
                    ((float*)Cv)[(size_t)(rrow + i) * N + ccol] = v;
            }
        }
}

// ---------------- fused MFMA flash attention, dbuf reg-staged (T14) ----------------
// Block: 256 thr (4 waves), QBLK=64, KBLK=64. One barrier per tile.
// Per tile: {write LDS(t+1) from regs | issue loads(t+2) | compute(t)}.
// V staged as Vt[d][k] pairs via ds_write_b32 (chunk-XOR swizzle by d>>3).
__global__ __launch_bounds__(256, 2) void attn_mfma(
    const short* __restrict__ qkv,
    const ushort* __restrict__ biasT,
    short* __restrict__ attn_o) {
    __shared__ short Ks[2][64 * 64];
    __shared__ short Vt[2][64 * 72];
    __shared__ short Pb[4][16 * 72];

    int tid = threadIdx.x, w = tid >> 6, l = tid & 63;
    int g = l >> 4, c16 = l & 15;
    int qt = blockIdx.x & 31, bh = blockIdx.x >> 5;
    int h = bh % H_, b = bh / H_;
    int q0 = qt * 64;
    const int QS = 3 * D_;
    const short* kvbase = qkv + (size_t)b * T_ * QS;

    // Q fragments (A-operand)
    bf16x8 qf[2];
    {
        int qrow = q0 + w * 16 + c16;
        const short* qp = kvbase + (size_t)qrow * QS + h * HD_;
        qf[0] = *(const bf16x8*)(qp + g * 8);
        qf[1] = *(const bf16x8*)(qp + 32 + g * 8);
    }
    const ushort* bptr[4];
#pragma unroll
    for (int i = 0; i < 4; ++i)
        bptr[i] = biasT + (size_t)h * T_ * T_ + (size_t)(q0 + w * 16 + g * 4 + i) * T_;

    // K staging geometry: rows krow, krow+32; seg swizzled
    int krow = tid >> 3, kseg = tid & 7;
    int kx = (kseg ^ (krow & 7)) << 3;  // (krow+32)&7 == krow&7
    const short* kgp = kvbase + D_ + h * HD_ + kseg * 8;
    // V staging geometry: rows vk0, vk0+1 for 8 d at vd0
    int vk0 = (tid & 31) * 2, vd0 = (tid >> 5) * 8;
    int vbase = ((((vk0 >> 3) ^ (vd0 >> 3)) & 7) << 3) + (vk0 & 7);
    const short* vgp = kvbase + 2 * D_ + h * HD_ + vd0;

    f32x4 zero = {0.f, 0.f, 0.f, 0.f};
    f32x4 oacc[4];
#pragma unroll
    for (int nf = 0; nf < 4; ++nf) oacc[nf] = zero;
    float lsum[4] = {0.f, 0.f, 0.f, 0.f};

    bf16x8 kr0, kr1, vr0, vr1;
    // load tile 0 into regs
    kr0 = *(const bf16x8*)(kgp + (size_t)krow * QS);
    kr1 = *(const bf16x8*)(kgp + (size_t)(krow + 32) * QS);
    vr0 = *(const bf16x8*)(vgp + (size_t)vk0 * QS);
    vr1 = *(const bf16x8*)(vgp + (size_t)(vk0 + 1) * QS);
    // write buf0 (no reads before first barrier)
    *(bf16x8*)&Ks[0][krow * 64 + kx] = kr0;
    *(bf16x8*)&Ks[0][(krow + 32) * 64 + kx] = kr1;
#pragma unroll
    for (int j = 0; j < 8; ++j) {
        unsigned pr = (unsigned)(ushort)vr0[j] | ((unsigned)(ushort)vr1[j] << 16);
        *(unsigned*)&Vt[0][(vd0 + j) * 72 + vbase] = pr;
    }
    // load tile 1 into regs
    {
        const short* kg1 = kgp + (size_t)64 * QS;
        const short* vg1 = vgp + (size_t)64 * QS;
        kr0 = *(const bf16x8*)(kg1 + (size_t)krow * QS);
        kr1 = *(const bf16x8*)(kg1 + (size_t)(krow + 32) * QS);
        vr0 = *(const bf16x8*)(vg1 + (size_t)vk0 * QS);
        vr1 = *(const bf16x8*)(vg1 + (size_t)(vk0 + 1) * QS);
    }

    for (int t = 0; t < 32; ++t) {
        __syncthreads();
        const short* KsC = Ks[t & 1];
        const short* VtC = Vt[t & 1];
        short* KsN = Ks[(t + 1) & 1];
        short* VtN = Vt[(t + 1) & 1];
        // ---- write next-tile LDS from regs ----
        *(bf16x8*)&KsN[krow * 64 + kx] = kr0;
        *(bf16x8*)&KsN[(krow + 32) * 64 + kx] = kr1;
#pragma unroll
        for (int j = 0; j < 8; ++j) {
            unsigned pr = (unsigned)(ushort)vr0[j] | ((unsigned)(ushort)vr1[j] << 16);
            *(unsigned*)&VtN[(vd0 + j) * 72 + vbase] = pr;
        }
        // ---- issue loads for tile t+2 ----
        {
            int kb2 = ((t + 2) & 31) * 64;
            const short* kg2 = kgp + (size_t)kb2 * QS;
            const short* vg2 = vgp + (size_t)kb2 * QS;
            kr0 = *(const bf16x8*)(kg2 + (size_t)krow * QS);
            kr1 = *(const bf16x8*)(kg2 + (size_t)(krow + 32) * QS);
            vr0 = *(const bf16x8*)(vg2 + (size_t)vk0 * QS);
            vr1 = *(const bf16x8*)(vg2 + (size_t)(vk0 + 1) * QS);
        }
        // ---- bias loads for this tile ----
        int kb = t * 64;
        float bv[16];
#pragma unroll
        for (int nf = 0; nf < 4; ++nf)
#pragma unroll
            for (int i = 0; i < 4; ++i)
                bv[nf * 4 + i] =
                    __builtin_bit_cast(float, (unsigned)bptr[i][kb + nf * 16 + c16] << 16);
        // ---- QK^T ----
        f32x4 sac[4];
#pragma unroll
        for (int nf = 0; nf < 4; ++nf) sac[nf] = zero;
#pragma unroll
        for (int dk = 0; dk < 2; ++dk) {
#pragma unroll
            for (int nf = 0; nf < 4; ++nf) {
                int r = nf * 16 + c16;
                bf16x8 kf = *(const bf16x8*)&KsC[r * 64 + (((dk * 4 + g) ^ (r & 7)) << 3)];
                sac[nf] = __builtin_amdgcn_mfma_f32_16x16x32_bf16(qf[dk], kf, sac[nf], 0, 0, 0);
            }
        }
        // ---- static-max softmax (in place) ----
#pragma unroll
        for (int nf = 0; nf < 4; ++nf)
#pragma unroll
            for (int i = 0; i < 4; ++i) {
                float e = __expf(fmaf(sac[nf][i], 0.125f, bv[nf * 4 + i]));
                sac[nf][i] = e;
                lsum[i] += e;
            }
        // ---- P -> wave-private LDS (chunk-swizzled by g) ----
        short* pbw = &Pb[w][0];
#pragma unroll
        for (int nf = 0; nf < 4; ++nf) {
            int chunkbase = nf * 2 + (c16 >> 3);
            int kpos = c16 & 7;
#pragma unroll
            for (int i = 0; i < 4; ++i)
                pbw[(g * 4 + i) * 72 + (((chunkbase ^ g) & 7) << 3) + kpos] = f2bf(sac[nf][i]);
        }
        // ---- PV ----
#pragma unroll
        for (int dk = 0; dk < 2; ++dk) {
            bf16x8 pa = *(const bf16x8*)&pbw[c16 * 72 + (((dk * 4 + g) ^ (c16 >> 2)) & 7) * 8];
#pragma unroll
            for (int nf = 0; nf < 4; ++nf) {
                int d = nf * 16 + c16;
                bf16x8 vb = *(const bf16x8*)&VtC[d * 72 + (((dk * 4 + g) ^ (d >> 3)) & 7) * 8];
                oacc[nf] = __builtin_amdgcn_mfma_f32_16x16x32_bf16(pa, vb, oacc[nf], 0, 0, 0);
            }
        }
    }

    // ---- one-time denominator reduction across the 16 lanes of each row ----
#pragma unroll
    for (int i = 0; i < 4; ++i) {
#pragma unroll
        for (int off = 1; off < 16; off <<= 1) lsum[i] += __shfl_xor(lsum[i], off, 64);
    }

    // ---- finalize ----
#pragma unroll
    for (int nf = 0; nf < 4; ++nf)
#pragma unroll
        for (int i = 0; i < 4; ++i) {
            float o = oacc[nf][i] / lsum[i];
            int qq = q0 + w * 16 + g * 4 + i;
            attn_o[(size_t)(b * T_ + qq) * D_ + h * HD_ + nf * 16 + c16] = f2bf(o);
        }
}

// ---------------- launcher ----------------
extern "C" void kernel_launch(void* const* d_in, const int* in_sizes, int n_in,
                              void* d_out, int out_size, void* d_ws, size_t ws_size,
                              hipStream_t stream) {
    const float* x = (const float*)d_in[0];
    const int* rowp = (const int*)d_in[1];
    const int* colp = (const int*)d_in[2];
    const int* drowp = (const int*)d_in[3];
    const int* dcolp = (const int*)d_in[4];
    const int* didp = (const int*)d_in[5];
    // d_in[6] = is_sep (bool) — unused: is_sep <=> demo_id < 0 by construction
    const float* ln1_w = (const float*)d_in[7];
    const float* ln1_b = (const float*)d_in[8];
    const float* ln2_w = (const float*)d_in[9];
    const float* ln2_b = (const float*)d_in[10];
    const float* qkv_w = (const float*)d_in[11];
    const float* qkv_b = (const float*)d_in[12];
    const float* proj_w = (const float*)d_in[13];
    const float* proj_b = (const float*)d_in[14];
    const float* ff1_w = (const float*)d_in[15];
    const float* ff1_b = (const float*)d_in[16];
    const float* ff2_w = (const float*)d_in[17];
    const float* ff2_b = (const float*)d_in[18];
    const float* rel_emb = (const float*)d_in[19];
    const float* demo_emb = (const float*)d_in[20];
    float* out = (float*)d_out;

    const int M = B_ * T_;  // 4096
    char* p = (char*)d_ws;
    short* h1 = (short*)p;     p += (size_t)M * D_ * 2;
    short* qkvb = (short*)p;   p += (size_t)M * 3 * D_ * 2;
    short* attn_o = (short*)p; p += (size_t)M * D_ * 2;
    short* qkvt = (short*)p;   p += (size_t)(3 * D_) * D_ * 2;
    short* projt = (short*)p;  p += (size_t)D_ * D_ * 2;
    short* ff1t = (short*)p;   p += (size_t)FF_ * D_ * 2;
    short* ff2t = (short*)p;   p += (size_t)D_ * FF_ * 2;
    // overlay: biasT (100.7 MB, live until attention) aliases x2+h2+ffact.
    float* x2 = (float*)p;
    short* h2 = (short*)(p + (size_t)M * D_ * 4);
    short* ffact = (short*)(p + (size_t)M * D_ * 4 + (size_t)M * D_ * 2);
    ushort* biasT = (ushort*)p;

    // ---- precompute ----
    bias_build<<<dim3(T_ / 64, T_ / 16), 256, 0, stream>>>(
        rowp, colp, drowp, dcolp, didp, rel_emb, demo_emb, biasT);
    tcast_kernel<<<dim3(3 * D_ / 32, D_ / 32), 256, 0, stream>>>(qkv_w, qkvt, D_, 3 * D_);
    tcast_kernel<<<dim3(D_ / 32, D_ / 32), 256, 0, stream>>>(proj_w, projt, D_, D_);
    tcast_kernel<<<dim3(FF_ / 32, D_ / 32), 256, 0, stream>>>(ff1_w, ff1t, D_, FF_);
    tcast_kernel<<<dim3(D_ / 32, FF_ / 32), 256, 0, stream>>>(ff2_w, ff2t, FF_, D_);

    // ---- main pipeline ----
    ln_bf16_kernel<<<dim3(M / 4), 256, 0, stream>>>(x, ln1_w, ln1_b, h1);

    gemm_bf16<EPI_NONE, 1><<<dim3(3 * D_ / 128, M / 128), 256, 0, stream>>>(
        h1, qkvt, qkv_b, nullptr, qkvb, M, 3 * D_, D_);

    attn_mfma<<<dim3(B_ * H_ * (T_ / 64)), 256, 0, stream>>>(qkvb, biasT, attn_o);

    gemm_bf16<EPI_RES, 0><<<dim3(D_ / 128, M / 128), 256, 0, stream>>>(
        attn_o, projt, proj_b, x, x2, M, D_, D_);

    ln_bf16_kernel<<<dim3(M / 4), 256, 0, stream>>>(x2, ln2_w, ln2_b, h2);

    gemm_bf16<EPI_GELU, 1><<<dim3(FF_ / 128, M / 128), 256, 0, stream>>>(
        h2, ff1t, ff1_b, nullptr, ffact, M, FF_, D_);

    gemm_bf16<EPI_RES, 0><<<dim3(D_ / 128, M / 128), 256, 0, stream>>>(
        ffact, ff2t, ff2_b, x2, out, M, D_, FF_);
}

// Round 10
// 242.884 us; speedup vs baseline: 2.2929x; 1.0825x over previous
//
#include <hip/hip_runtime.h>
#include <hip/hip_bf16.h>
#include <hip/hip_fp16.h>
#include <math.h>

#define G_ 32
#define H_ 12
#define D_ 768
#define HD_ 64
#define FF_ 3072
#define B_ 2
#define T_ 2048
#define SPAN_ 63
#define SPANC_ 129
#define EPSF 1e-5f

typedef short bf16x8 __attribute__((ext_vector_type(8)));
typedef short short4v __attribute__((ext_vector_type(4)));
typedef float f32x4 __attribute__((ext_vector_type(4)));

__device__ __forceinline__ short f2bf(float f) {
    unsigned u = __builtin_bit_cast(unsigned, f);
    u = u + 0x7FFFu + ((u >> 16) & 1u);
    return (short)(u >> 16);
}

// OCP e5m2 = top byte of IEEE fp16 (same exponent bias, denormals align)
__device__ __forceinline__ unsigned char f2e5m2(float f) {
    unsigned short u = __half_as_ushort(__float2half(f));  // RNE to fp16
    u = (unsigned short)(u + 0x7F + ((u >> 8) & 1));       // RNE to top 8 bits
    return (unsigned char)(u >> 8);
}
__device__ __forceinline__ float e5m2f(unsigned u) {
    return __half2float(__ushort_as_half((unsigned short)(u << 8)));
}

// async global->LDS, 16B per lane; LDS dest = wave-uniform base + lane*16
__device__ __forceinline__ void gl_lds16(const void* g, void* l) {
    __builtin_amdgcn_global_load_lds(
        (const __attribute__((address_space(1))) unsigned int*)g,
        (__attribute__((address_space(3))) unsigned int*)l, 16, 0, 0);
}

// ---------------- LayerNorm (f32 in -> bf16 out): one wave per row ----------------
__global__ __launch_bounds__(256) void ln_bf16_kernel(const float* __restrict__ x,
                                                      const float* __restrict__ w,
                                                      const float* __restrict__ b,
                                                      short* __restrict__ out) {
    int wv = threadIdx.x >> 6;
    int lane = threadIdx.x & 63;
    int rowi = blockIdx.x * 4 + wv;
    const float* xr = x + (size_t)rowi * D_;
    float vals[12];
    float s = 0.f;
#pragma unroll
    for (int i = 0; i < 12; ++i) { vals[i] = xr[lane + i * 64]; s += vals[i]; }
#pragma unroll
    for (int off = 32; off > 0; off >>= 1) s += __shfl_xor(s, off, 64);
    float mean = s * (1.0f / D_);
    float vs = 0.f;
#pragma unroll
    for (int i = 0; i < 12; ++i) { float d = vals[i] - mean; vs += d * d; }
#pragma unroll
    for (int off = 32; off > 0; off >>= 1) vs += __shfl_xor(vs, off, 64);
    float rstd = rsqrtf(vs * (1.0f / D_) + EPSF);
    short* outr = out + (size_t)rowi * D_;
#pragma unroll
    for (int i = 0; i < 12; ++i) {
        int c = lane + i * 64;
        outr[c] = f2bf((vals[i] - mean) * rstd * w[c] + b[c]);
    }
}

// ---------------- transpose-cast: W [K][N] f32 -> Wt [N][K] bf16 ----------------
__global__ __launch_bounds__(256) void tcast_kernel(const float* __restrict__ W,
                                                    short* __restrict__ Wt,
                                                    int K, int N) {
    __shared__ float t[32][33];
    int n0 = blockIdx.x * 32, k0 = blockIdx.y * 32;
    int tid = threadIdx.x;
    int r = tid >> 3, c4 = (tid & 7) * 4;
    float4 v = *(const float4*)(W + (size_t)(k0 + r) * N + n0 + c4);
    t[r][c4 + 0] = v.x; t[r][c4 + 1] = v.y; t[r][c4 + 2] = v.z; t[r][c4 + 3] = v.w;
    __syncthreads();
    short4v o;
    o[0] = f2bf(t[c4 + 0][r]); o[1] = f2bf(t[c4 + 1][r]);
    o[2] = f2bf(t[c4 + 2][r]); o[3] = f2bf(t[c4 + 3][r]);
    *(short4v*)(Wt + (size_t)(n0 + r) * K + k0 + c4) = o;
}

// ---------------- bias materialization: biasT[h][q][k] fp8-e5m2 ----------------
__global__ __launch_bounds__(256) void bias_build(
    const int* __restrict__ rowp, const int* __restrict__ colp,
    const int* __restrict__ drowp, const int* __restrict__ dcolp,
    const int* __restrict__ didp,
    const float* __restrict__ rel_emb, const float* __restrict__ demo_emb,
    unsigned char* __restrict__ biasT) {
    __shared__ unsigned char patch[12][16][80];
    int k0 = blockIdx.x * 64, q0 = blockIdx.y * 16;
    int tid = threadIdx.x;
    int qi = tid >> 4, kq = (tid & 15) * 4;
    int q = q0 + qi;
    int idq = didp[q];
    int rq = rowp[q], cq = colp[q], drq = drowp[q], dcq = dcolp[q];
    float bvs[4][12];
#pragma unroll
    for (int j = 0; j < 4; ++j) {
        int k = k0 + kq + j;
        int idk = didp[k];
        float4 v0 = {0.f, 0.f, 0.f, 0.f}, v1 = v0, v2 = v0;
        if (idq >= 0 && idk >= 0) {
            int dr = min(max(rq - rowp[k], -(G_ - 1)), G_ - 1) + (G_ - 1);
            int dc = min(max(cq - colp[k], -(G_ - 1)), G_ - 1) + (G_ - 1);
            const float* rp = rel_emb + (size_t)(dr * SPAN_ + dc) * 12;
            v0 = *(const float4*)rp;
            v1 = *(const float4*)(rp + 4);
            v2 = *(const float4*)(rp + 8);
            if (idq == idk) {
                int ddr = min(max(drq - drowp[k], -(G_ - 1)), G_ - 1) + (G_ - 1);
                int ddc = min(max(dcq - dcolp[k], -2 * G_), 2 * G_) + 2 * G_;
                const float* dp = demo_emb + (size_t)(ddr * SPANC_ + ddc) * 12;
                float4 w0 = *(const float4*)dp;
                float4 w1 = *(const float4*)(dp + 4);
                float4 w2 = *(const float4*)(dp + 8);
                v0.x += w0.x; v0.y += w0.y; v0.z += w0.z; v0.w += w0.w;
                v1.x += w1.x; v1.y += w1.y; v1.z += w1.z; v1.w += w1.w;
                v2.x += w2.x; v2.y += w2.y; v2.z += w2.z; v2.w += w2.w;
            }
        }
        bvs[j][0] = v0.x; bvs[j][1] = v0.y; bvs[j][2] = v0.z; bvs[j][3] = v0.w;
        bvs[j][4] = v1.x; bvs[j][5] = v1.y; bvs[j][6] = v1.z; bvs[j][7] = v1.w;
        bvs[j][8] = v2.x; bvs[j][9] = v2.y; bvs[j][10] = v2.z; bvs[j][11] = v2.w;
    }
#pragma unroll
    for (int h = 0; h < 12; ++h) {
        uchar4 pk;
        pk.x = f2e5m2(bvs[0][h]); pk.y = f2e5m2(bvs[1][h]);
        pk.z = f2e5m2(bvs[2][h]); pk.w = f2e5m2(bvs[3][h]);
        *(uchar4*)&patch[h][qi][kq] = pk;
    }
    __syncthreads();
    // writeout: 12 planes x 16 rows x 64B = 768 chunks of 16B
    for (int c = tid; c < 768; c += 256) {
        int rowid = c >> 2, off = (c & 3) * 16;
        int h = rowid >> 4, q2 = rowid & 15;
        *(uint4*)(biasT + (size_t)h * T_ * T_ + (size_t)(q0 + q2) * T_ + k0 + off) =
            *(const uint4*)&patch[h][q2][off];
    }
}

// ---------------- bf16 MFMA GEMM: C = A[M][K] * Bt[N][K]^T ----------------
// Tile BM x 128, BK=64, 4 waves. BM=128: waves 2x2 (64x64 each); BM=64: 2x2 (32x64).
enum { EPI_NONE = 0, EPI_RES = 1, EPI_GELU = 2 };

template <int EPI, int BF16OUT, int BM>
__global__ __launch_bounds__(256, 2) void gemm_bf16(const short* __restrict__ A,
                                                    const short* __restrict__ Bt,
                                                    const float* __restrict__ bias,
                                                    const float* __restrict__ res,
                                                    void* __restrict__ Cv,
                                                    int M, int N, int K) {
    __shared__ short As[BM * 64];
    __shared__ short Bs[128 * 64];
    constexpr int WM = BM / 2;       // rows per wave
    constexpr int MF = WM / 16;      // m fragments per wave
    int tid = threadIdx.x;
    int l = tid & 63;
    int w = tid >> 6;
    int wm = w >> 1, wn = w & 1;
    int row0 = blockIdx.y * BM, col0 = blockIdx.x * 128;
    int g = l >> 4, c16 = l & 15;
    f32x4 zero = {0.f, 0.f, 0.f, 0.f};
    f32x4 acc[MF][4];
#pragma unroll
    for (int m = 0; m < MF; ++m)
#pragma unroll
        for (int n = 0; n < 4; ++n) acc[m][n] = zero;

    int srowA = w * (BM / 4) + (l >> 3);
    int srowB = w * 32 + (l >> 3);
    int sseg0 = (l & 7);

    for (int k0 = 0; k0 < K; k0 += 64) {
#pragma unroll
        for (int inst = 0; inst < BM / 32; ++inst) {
            int arow = srowA + inst * 8;
            int seg = sseg0 ^ (arow & 7);
            gl_lds16(A + (size_t)(row0 + arow) * K + k0 + seg * 8,
                     &As[(w * (BM / 4) + inst * 8) * 64]);
        }
#pragma unroll
        for (int inst = 0; inst < 4; ++inst) {
            int brow = srowB + inst * 8;
            int seg = sseg0 ^ (brow & 7);
            gl_lds16(Bt + (size_t)(col0 + brow) * K + k0 + seg * 8,
                     &Bs[(w * 32 + inst * 8) * 64]);
        }
        __syncthreads();
#pragma unroll
        for (int dk = 0; dk < 2; ++dk) {
            bf16x8 af[MF], bfr[4];
#pragma unroll
            for (int m = 0; m < MF; ++m) {
                int r = wm * WM + m * 16 + c16;
                af[m] = *(const bf16x8*)&As[r * 64 + (((dk * 4 + g) ^ (r & 7)) << 3)];
            }
#pragma unroll
            for (int n = 0; n < 4; ++n) {
                int r = wn * 64 + n * 16 + c16;
                bfr[n] = *(const bf16x8*)&Bs[r * 64 + (((dk * 4 + g) ^ (r & 7)) << 3)];
            }
#pragma unroll
            for (int m = 0; m < MF; ++m)
#pragma unroll
                for (int n = 0; n < 4; ++n)
                    acc[m][n] = __builtin_amdgcn_mfma_f32_16x16x32_bf16(af[m], bfr[n], acc[m][n], 0, 0, 0);
        }
        __syncthreads();
    }

#pragma unroll
    for (int m = 0; m < MF; ++m)
#pragma unroll
        for (int n = 0; n < 4; ++n) {
            int rrow = row0 + wm * WM + m * 16 + g * 4;
            int ccol = col0 + wn * 64 + n * 16 + c16;
            float bv = bias[ccol];
#pragma unroll
            for (int i = 0; i < 4; ++i) {
                float v = acc[m][n][i] + bv;
                if (EPI == EPI_GELU) v = 0.5f * v * (1.f + erff(v * 0.70710678118f));
                if (EPI == EPI_RES) v += res[(size_t)(rrow + i) * N + ccol];
                if (BF16OUT)
                    ((short*)Cv)[(size_t)(rrow + i) * N + ccol] = f2bf(v);
                else
                    ((float*)Cv)[(size_t)(rrow + i) * N + ccol] = v;
            }
        }
}

// ---------------- fused MFMA flash attention, dbuf reg-staged, fp8 bias ----------------
// Block: 256 thr (4 waves), QBLK=64, KBLK=64. One barrier per tile.
// XCD-chunk swizzled blockIdx (768 = 8 x 96, bijective).
__global__ __launch_bounds__(256, 2) void attn_mfma(
    const short* __restrict__ qkv,
    const unsigned char* __restrict__ biasT,
    short* __restrict__ attn_o) {
    __shared__ short Ks[2][64 * 64];
    __shared__ short Vt[2][64 * 72];
    __shared__ short Pb[4][16 * 72];

    int tid = threadIdx.x, w = tid >> 6, l = tid & 63;
    int g = l >> 4, c16 = l & 15;
    int bid = blockIdx.x;
    int nb = (bid & 7) * 96 + (bid >> 3);   // XCD-chunk swizzle
    int qt = nb & 31, bh = nb >> 5;
    int h = bh % H_, b = bh / H_;
    int q0 = qt * 64;
    const int QS = 3 * D_;
    const short* kvbase = qkv + (size_t)b * T_ * QS;

    // Q fragments (A-operand)
    bf16x8 qf[2];
    {
        int qrow = q0 + w * 16 + c16;
        const short* qp = kvbase + (size_t)qrow * QS + h * HD_;
        qf[0] = *(const bf16x8*)(qp + g * 8);
        qf[1] = *(const bf16x8*)(qp + 32 + g * 8);
    }
    const unsigned char* bptr[4];
#pragma unroll
    for (int i = 0; i < 4; ++i)
        bptr[i] = biasT + (size_t)h * T_ * T_ + (size_t)(q0 + w * 16 + g * 4 + i) * T_;

    int krow = tid >> 3, kseg = tid & 7;
    int kx = (kseg ^ (krow & 7)) << 3;
    const short* kgp = kvbase + D_ + h * HD_ + kseg * 8;
    int vk0 = (tid & 31) * 2, vd0 = (tid >> 5) * 8;
    int vbase = ((((vk0 >> 3) ^ (vd0 >> 3)) & 7) << 3) + (vk0 & 7);
    const short* vgp = kvbase + 2 * D_ + h * HD_ + vd0;

    f32x4 zero = {0.f, 0.f, 0.f, 0.f};
    f32x4 oacc[4];
#pragma unroll
    for (int nf = 0; nf < 4; ++nf) oacc[nf] = zero;
    float lsum[4] = {0.f, 0.f, 0.f, 0.f};

    bf16x8 kr0, kr1, vr0, vr1;
    kr0 = *(const bf16x8*)(kgp + (size_t)krow * QS);
    kr1 = *(const bf16x8*)(kgp + (size_t)(krow + 32) * QS);
    vr0 = *(const bf16x8*)(vgp + (size_t)vk0 * QS);
    vr1 = *(const bf16x8*)(vgp + (size_t)(vk0 + 1) * QS);
    *(bf16x8*)&Ks[0][krow * 64 + kx] = kr0;
    *(bf16x8*)&Ks[0][(krow + 32) * 64 + kx] = kr1;
#pragma unroll
    for (int j = 0; j < 8; ++j) {
        unsigned pr = (unsigned)(ushort)vr0[j] | ((unsigned)(ushort)vr1[j] << 16);
        *(unsigned*)&Vt[0][(vd0 + j) * 72 + vbase] = pr;
    }
    {
        const short* kg1 = kgp + (size_t)64 * QS;
        const short* vg1 = vgp + (size_t)64 * QS;
        kr0 = *(const bf16x8*)(kg1 + (size_t)krow * QS);
        kr1 = *(const bf16x8*)(kg1 + (size_t)(krow + 32) * QS);
        vr0 = *(const bf16x8*)(vg1 + (size_t)vk0 * QS);
        vr1 = *(const bf16x8*)(vg1 + (size_t)(vk0 + 1) * QS);
    }

    for (int t = 0; t < 32; ++t) {
        __syncthreads();
        const short* KsC = Ks[t & 1];
        const short* VtC = Vt[t & 1];
        short* KsN = Ks[(t + 1) & 1];
        short* VtN = Vt[(t + 1) & 1];
        *(bf16x8*)&KsN[krow * 64 + kx] = kr0;
        *(bf16x8*)&KsN[(krow + 32) * 64 + kx] = kr1;
#pragma unroll
        for (int j = 0; j < 8; ++j) {
            unsigned pr = (unsigned)(ushort)vr0[j] | ((unsigned)(ushort)vr1[j] << 16);
            *(unsigned*)&VtN[(vd0 + j) * 72 + vbase] = pr;
        }
        {
            int kb2 = ((t + 2) & 31) * 64;
            const short* kg2 = kgp + (size_t)kb2 * QS;
            const short* vg2 = vgp + (size_t)kb2 * QS;
            kr0 = *(const bf16x8*)(kg2 + (size_t)krow * QS);
            kr1 = *(const bf16x8*)(kg2 + (size_t)(krow + 32) * QS);
            vr0 = *(const bf16x8*)(vg2 + (size_t)vk0 * QS);
            vr1 = *(const bf16x8*)(vg2 + (size_t)(vk0 + 1) * QS);
        }
        // ---- fp8 bias loads for this tile (coalesced bytes) ----
        int kb = t * 64;
        float bv[16];
#pragma unroll
        for (int nf = 0; nf < 4; ++nf)
#pragma unroll
            for (int i = 0; i < 4; ++i)
                bv[nf * 4 + i] = e5m2f(bptr[i][kb + nf * 16 + c16]);
        // ---- QK^T ----
        f32x4 sac[4];
#pragma unroll
        for (int nf = 0; nf < 4; ++nf) sac[nf] = zero;
#pragma unroll
        for (int dk = 0; dk < 2; ++dk) {
#pragma unroll
            for (int nf = 0; nf < 4; ++nf) {
                int r = nf * 16 + c16;
                bf16x8 kf = *(const bf16x8*)&KsC[r * 64 + (((dk * 4 + g) ^ (r & 7)) << 3)];
                sac[nf] = __builtin_amdgcn_mfma_f32_16x16x32_bf16(qf[dk], kf, sac[nf], 0, 0, 0);
            }
        }
        // ---- static-max softmax ----
#pragma unroll
        for (int nf = 0; nf < 4; ++nf)
#pragma unroll
            for (int i = 0; i < 4; ++i) {
                float e = __expf(fmaf(sac[nf][i], 0.125f, bv[nf * 4 + i]));
                sac[nf][i] = e;
                lsum[i] += e;
            }
        // ---- P -> wave-private LDS (chunk-swizzled by g) ----
        short* pbw = &Pb[w][0];
#pragma unroll
        for (int nf = 0; nf < 4; ++nf) {
            int chunkbase = nf * 2 + (c16 >> 3);
            int kpos = c16 & 7;
#pragma unroll
            for (int i = 0; i < 4; ++i)
                pbw[(g * 4 + i) * 72 + (((chunkbase ^ g) & 7) << 3) + kpos] = f2bf(sac[nf][i]);
        }
        // ---- PV ----
#pragma unroll
        for (int dk = 0; dk < 2; ++dk) {
            bf16x8 pa = *(const bf16x8*)&pbw[c16 * 72 + (((dk * 4 + g) ^ (c16 >> 2)) & 7) * 8];
#pragma unroll
            for (int nf = 0; nf < 4; ++nf) {
                int d = nf * 16 + c16;
                bf16x8 vb = *(const bf16x8*)&VtC[d * 72 + (((dk * 4 + g) ^ (d >> 3)) & 7) * 8];
                oacc[nf] = __builtin_amdgcn_mfma_f32_16x16x32_bf16(pa, vb, oacc[nf], 0, 0, 0);
            }
        }
    }

#pragma unroll
    for (int i = 0; i < 4; ++i) {
#pragma unroll
        for (int off = 1; off < 16; off <<= 1) lsum[i] += __shfl_xor(lsum[i], off, 64);
    }

#pragma unroll
    for (int nf = 0; nf < 4; ++nf)
#pragma unroll
        for (int i = 0; i < 4; ++i) {
            float o = oacc[nf][i] / lsum[i];
            int qq = q0 + w * 16 + g * 4 + i;
            attn_o[(size_t)(b * T_ + qq) * D_ + h * HD_ + nf * 16 + c16] = f2bf(o);
        }
}

// ---------------- launcher ----------------
extern "C" void kernel_launch(void* const* d_in, const int* in_sizes, int n_in,
                              void* d_out, int out_size, void* d_ws, size_t ws_size,
                              hipStream_t stream) {
    const float* x = (const float*)d_in[0];
    const int* rowp = (const int*)d_in[1];
    const int* colp = (const int*)d_in[2];
    const int* drowp = (const int*)d_in[3];
    const int* dcolp = (const int*)d_in[4];
    const int* didp = (const int*)d_in[5];
    // d_in[6] = is_sep (bool) — unused: is_sep <=> demo_id < 0 by construction
    const float* ln1_w = (const float*)d_in[7];
    const float* ln1_b = (const float*)d_in[8];
    const float* ln2_w = (const float*)d_in[9];
    const float* ln2_b = (const float*)d_in[10];
    const float* qkv_w = (const float*)d_in[11];
    const float* qkv_b = (const float*)d_in[12];
    const float* proj_w = (const float*)d_in[13];
    const float* proj_b = (const float*)d_in[14];
    const float* ff1_w = (const float*)d_in[15];
    const float* ff1_b = (const float*)d_in[16];
    const float* ff2_w = (const float*)d_in[17];
    const float* ff2_b = (const float*)d_in[18];
    const float* rel_emb = (const float*)d_in[19];
    const float* demo_emb = (const float*)d_in[20];
    float* out = (float*)d_out;

    const int M = B_ * T_;  // 4096
    char* p = (char*)d_ws;
    short* h1 = (short*)p;     p += (size_t)M * D_ * 2;
    short* qkvb = (short*)p;   p += (size_t)M * 3 * D_ * 2;
    short* attn_o = (short*)p; p += (size_t)M * D_ * 2;
    short* qkvt = (short*)p;   p += (size_t)(3 * D_) * D_ * 2;
    short* projt = (short*)p;  p += (size_t)D_ * D_ * 2;
    short* ff1t = (short*)p;   p += (size_t)FF_ * D_ * 2;
    short* ff2t = (short*)p;   p += (size_t)D_ * FF_ * 2;
    // overlay: biasT (50.3 MB fp8, live until attention) aliases x2+h2+ffact.
    float* x2 = (float*)p;
    short* h2 = (short*)(p + (size_t)M * D_ * 4);
    short* ffact = (short*)(p + (size_t)M * D_ * 4 + (size_t)M * D_ * 2);
    unsigned char* biasT = (unsigned char*)p;

    // ---- precompute ----
    bias_build<<<dim3(T_ / 64, T_ / 16), 256, 0, stream>>>(
        rowp, colp, drowp, dcolp, didp, rel_emb, demo_emb, biasT);
    tcast_kernel<<<dim3(3 * D_ / 32, D_ / 32), 256, 0, stream>>>(qkv_w, qkvt, D_, 3 * D_);
    tcast_kernel<<<dim3(D_ / 32, D_ / 32), 256, 0, stream>>>(proj_w, projt, D_, D_);
    tcast_kernel<<<dim3(FF_ / 32, D_ / 32), 256, 0, stream>>>(ff1_w, ff1t, D_, FF_);
    tcast_kernel<<<dim3(D_ / 32, FF_ / 32), 256, 0, stream>>>(ff2_w, ff2t, FF_, D_);

    // ---- main pipeline ----
    ln_bf16_kernel<<<dim3(M / 4), 256, 0, stream>>>(x, ln1_w, ln1_b, h1);

    gemm_bf16<EPI_NONE, 1, 128><<<dim3(3 * D_ / 128, M / 128), 256, 0, stream>>>(
        h1, qkvt, qkv_b, nullptr, qkvb, M, 3 * D_, D_);

    attn_mfma<<<dim3(B_ * H_ * (T_ / 64)), 256, 0, stream>>>(qkvb, biasT, attn_o);

    gemm_bf16<EPI_RES, 0, 64><<<dim3(D_ / 128, M / 64), 256, 0, stream>>>(
        attn_o, projt, proj_b, x, x2, M, D_, D_);

    ln_bf16_kernel<<<dim3(M / 4), 256, 0, stream>>>(x2, ln2_w, ln2_b, h2);

    gemm_bf16<EPI_GELU, 1, 128><<<dim3(FF_ / 128, M / 128), 256, 0, stream>>>(
        h2, ff1t, ff1_b, nullptr, ffact, M, FF_, D_);

    gemm_bf16<EPI_RES, 0, 64><<<dim3(D_ / 128, M / 64), 256, 0, stream>>>(
        ffact, ff2t, ff2_b, x2, out, M, D_, FF_);
}